// Round 9
// baseline (1208.489 us; speedup 1.0000x reference)
//
#include <hip/hip_runtime.h>

using f32x4  = __attribute__((ext_vector_type(4))) float;
using short8 = __attribute__((ext_vector_type(8))) short;
using u64x2  = __attribute__((ext_vector_type(2))) unsigned long long;

__device__ __forceinline__ unsigned short f2bf(float f) {
  unsigned u = __builtin_bit_cast(unsigned, f);
  u = (u + 0x7FFFu + ((u >> 16) & 1u)) >> 16;
  return (unsigned short)u;
}
__device__ __forceinline__ float bf2f(unsigned short s) {
  return __builtin_bit_cast(float, ((unsigned)s) << 16);
}
__device__ __forceinline__ double u2d(unsigned long long u) {
  return __builtin_bit_cast(double, u);
}
__device__ __forceinline__ unsigned long long d2u(double d) {
  return __builtin_bit_cast(unsigned long long, d);
}
__device__ __forceinline__ unsigned cvt_pk_bf16(float lo, float hi) {
  unsigned r;
  asm("v_cvt_pk_bf16_f32 %0, %1, %2" : "=v"(r) : "v"(lo), "v"(hi));
  return r;
}

// DPP f64 max (reduction; non-receiving lanes get 0 which is < any candidate).
template <int CTRL>
__device__ __forceinline__ double dpp_max_f64(double best) {
  unsigned long long u = d2u(best);
  int lo32 = (int)(unsigned)u;
  int hi32 = (int)(unsigned)(u >> 32);
  int plo = __builtin_amdgcn_update_dpp(0, lo32, CTRL, 0xF, 0xF, true);
  int phi = __builtin_amdgcn_update_dpp(0, hi32, CTRL, 0xF, 0xF, true);
  unsigned long long p =
      ((unsigned long long)(unsigned)phi << 32) | (unsigned long long)(unsigned)plo;
  return fmax(best, u2d(p));
}
// DPP f64 min (bound_ctrl=false: non-receiving lanes keep self).
template <int CTRL>
__device__ __forceinline__ double dpp_min_f64(double v) {
  unsigned long long u = d2u(v);
  int lo32 = (int)(unsigned)u;
  int hi32 = (int)(unsigned)(u >> 32);
  int plo = __builtin_amdgcn_update_dpp(lo32, lo32, CTRL, 0xF, 0xF, false);
  int phi = __builtin_amdgcn_update_dpp(hi32, hi32, CTRL, 0xF, 0xF, false);
  unsigned long long p =
      ((unsigned long long)(unsigned)phi << 32) | (unsigned long long)(unsigned)plo;
  return fmin(v, u2d(p));
}

#define BCAP 384

union __align__(16) SmemMega {
  struct { float4 sp4[4096]; unsigned long long scand[2][16]; int sfar[1024]; } f; // FPS
  float tile[64][65];                                                              // prep
  struct { float4 sp[4096]; unsigned long long spk[4][BCAP]; } bq;                 // ball
  struct { unsigned short A[64][104]; unsigned short W[64][104]; float sred[4][2][64]; } g1;
};

struct MegaP {
  const float* xyz; const float* points;
  float* out0; float* out2;
  int* fpsidx; float4* nq4;
  unsigned short* pT; float4* xyz4;
  const float* w0; const float* w1; const float* w2;
  unsigned short* wb0; unsigned short* wb1; unsigned short* wb2;
  const float* b0;
  unsigned short* xbuf; float* part;
  int* bidx;
  int* prog; int* prepcnt; int* wflag; int* ballprog;
  int nc;
};

// ---- publish one FPS slot (identical numerics to the old epilogue) ----
__device__ __forceinline__ void fps_publish(const MegaP& P, SmemMega& sm, int b, int k) {
  int fr = sm.f.sfar[k];
  float4 p = sm.f.sp4[fr];
  P.fpsidx[(b << 10) + k] = fr;
  P.out2[(b << 10) + k] = (float)fr;
  P.out0[(size_t)b * 3072 + k]        = p.x;
  P.out0[(size_t)b * 3072 + 1024 + k] = p.y;
  P.out0[(size_t)b * 3072 + 2048 + k] = p.z;
  float ps = __fadd_rn(__fadd_rn(__fmul_rn(p.x, p.x), __fmul_rn(p.y, p.y)), __fmul_rn(p.z, p.z));
  P.nq4[(b << 10) + k] = make_float4(p.x, p.y, p.z, ps);
}

// ---- prep tile (validated r8 body) ----
__device__ __forceinline__ void do_prep(int pb, SmemMega& sm, const MegaP& P) {
  int t = threadIdx.x;
  int b = pb >> 6, n0 = (pb & 63) << 6;
#pragma unroll
  for (int p = 0; p < 16; ++p) {
    int c = p * 4 + (t >> 6);
    sm.tile[c][t & 63] = P.points[(size_t)b * 262144 + (size_t)c * 4096 + n0 + (t & 63)];
  }
  if (t < 64) {
    int n = n0 + t;
    float x = P.xyz[(size_t)b * 12288 + n];
    float y = P.xyz[(size_t)b * 12288 + 4096 + n];
    float z = P.xyz[(size_t)b * 12288 + 8192 + n];
    float ps = __fadd_rn(__fadd_rn(__fmul_rn(x, x), __fmul_rn(y, y)), __fmul_rn(z, z));
    P.xyz4[(size_t)b * 4096 + n] = make_float4(x, y, z, ps);
  }
  __syncthreads();
  int nl = t >> 2, coff = (t & 3) * 16;
  unsigned v[8];
#pragma unroll
  for (int j = 0; j < 8; ++j)
    v[j] = cvt_pk_bf16(sm.tile[coff + 2 * j][nl], sm.tile[coff + 2 * j + 1][nl]);
  uint4* dst = reinterpret_cast<uint4*>(P.pT + ((size_t)b * 4096 + n0 + nl) * 64 + coff);
  dst[0] = make_uint4(v[0], v[1], v[2], v[3]);
  dst[1] = make_uint4(v[4], v[5], v[6], v[7]);
  __syncthreads();  // protect sm.tile before next loop tile
}

// ---- ball tile (validated r8 body) ----
__device__ __forceinline__ void do_ball(int w, SmemMega& sm, const MegaP& P) {
  const unsigned long long INVP = 0x7149F2CAFFFFFFFFull;
  int t = threadIdx.x;
  int b = w >> 6;
  for (int i = t; i < 4096; i += 256) sm.bq.sp[i] = P.xyz4[(size_t)b * 4096 + i];
  __syncthreads();
  int lane = t & 63, wid = t >> 6;
  for (int r = 0; r < 4; ++r) {
    int q = w * 16 + r * 4 + wid;
    int qi = P.fpsidx[q];
    float4 Q = sm.bq.sp[qi];
    float qx = Q.x, qy = Q.y, qz = Q.z, qs = Q.w;
    int cnt = 0;
    for (int i = 0; i < 64; ++i) {
      int n = (i << 6) + lane;
      float4 Pp = sm.bq.sp[n];
      float dot = __fadd_rn(__fadd_rn(__fmul_rn(qx, Pp.x), __fmul_rn(qy, Pp.y)), __fmul_rn(qz, Pp.z));
      float d   = __fadd_rn(__fadd_rn(__fmul_rn(-2.f, dot), qs), Pp.w);
      bool in = (d <= 0.04f);
      unsigned long long m = __ballot(in);
      int pos = cnt + (int)__popcll(m & ((1ull << lane) - 1ull));
      if (in && pos < BCAP)
        sm.bq.spk[wid][pos] = ((unsigned long long)__builtin_bit_cast(unsigned, d) << 32) | (unsigned)n;
      cnt += (int)__popcll(m);
    }
    if (cnt > BCAP) cnt = BCAP;
    double c0, c1, c2, c3, c4, c5;
    {
      int s0 = lane, s1 = lane + 64, s2 = lane + 128, s3 = lane + 192, s4 = lane + 256, s5 = lane + 320;
      c0 = (s0 < cnt) ? u2d(sm.bq.spk[wid][s0]) : u2d(INVP);
      c1 = (s1 < cnt) ? u2d(sm.bq.spk[wid][s1]) : u2d(INVP);
      c2 = (s2 < cnt) ? u2d(sm.bq.spk[wid][s2]) : u2d(INVP);
      c3 = (s3 < cnt) ? u2d(sm.bq.spk[wid][s3]) : u2d(INVP);
      c4 = (s4 < cnt) ? u2d(sm.bq.spk[wid][s4]) : u2d(INVP);
      c5 = (s5 < cnt) ? u2d(sm.bq.spk[wid][s5]) : u2d(INVP);
    }
#define CE(a, b) { double mn_ = fmin(a, b), mx_ = fmax(a, b); a = mn_; b = mx_; }
    CE(c0, c1);
    CE(c1, c2); CE(c0, c1);
    CE(c2, c3); CE(c1, c2); CE(c0, c1);
    CE(c3, c4); CE(c2, c3); CE(c1, c2); CE(c0, c1);
    CE(c4, c5); CE(c3, c4); CE(c2, c3); CE(c1, c2); CE(c0, c1);
#undef CE
    int firstI = 0;
#pragma unroll 1
    for (int rr = 0; rr < 32; ++rr) {
      double h = c0;
      h = dpp_min_f64<0xB1>(h);
      h = dpp_min_f64<0x4E>(h);
      h = dpp_min_f64<0x124>(h);
      h = dpp_min_f64<0x128>(h);
      unsigned long long hu = d2u(h);
      int lo = (int)(unsigned)hu, hi = (int)(unsigned)(hu >> 32);
      unsigned long long r0 = ((unsigned long long)(unsigned)__builtin_amdgcn_readlane(hi, 0)  << 32) | (unsigned)__builtin_amdgcn_readlane(lo, 0);
      unsigned long long r1 = ((unsigned long long)(unsigned)__builtin_amdgcn_readlane(hi, 16) << 32) | (unsigned)__builtin_amdgcn_readlane(lo, 16);
      unsigned long long r2 = ((unsigned long long)(unsigned)__builtin_amdgcn_readlane(hi, 32) << 32) | (unsigned)__builtin_amdgcn_readlane(lo, 32);
      unsigned long long r3 = ((unsigned long long)(unsigned)__builtin_amdgcn_readlane(hi, 48) << 32) | (unsigned)__builtin_amdgcn_readlane(lo, 48);
      double ww = fmin(fmin(u2d(r0), u2d(r1)), fmin(u2d(r2), u2d(r3)));
      unsigned long long wu = d2u(ww);
      int wi = (int)(unsigned)wu;
      if (rr == 0) firstI = wi;
      int outv = (wu < INVP) ? wi : firstI;
      if (lane == 0) P.bidx[(size_t)q * 32 + rr] = outv;
      if (d2u(c0) == wu) { c0 = c1; c1 = c2; c2 = c3; c3 = c4; c4 = c5; c5 = u2d(INVP); }
    }
  }
  __syncthreads();  // protect sm.bq before next tile / flag
}

// ---- gemm1 tile (validated r8 body) ----
__device__ __forceinline__ void do_gemm1(int w, SmemMega& sm, const MegaP& P) {
  int t = threadIdx.x;
  int b = w >> 9;
  for (int e = t; e < 768; e += 256) {
    int o = e / 12, k8 = e - o * 12;
    *reinterpret_cast<uint4*>(&sm.g1.W[o][k8 * 8]) = reinterpret_cast<const uint4*>(P.wb0)[e];
  }
  {
    int rt = t >> 2, sub = t & 3;
    int q = (w << 1) + (rt >> 5);
    int n = P.bidx[(size_t)q * 32 + (rt & 31)];
    const uint4* src = reinterpret_cast<const uint4*>(P.pT + ((size_t)(b * 4096 + n)) * 64 + sub * 16);
    uint4 v0 = src[0], v1 = src[1];
    *reinterpret_cast<uint4*>(&sm.g1.A[rt][sub * 16])     = v0;
    *reinterpret_cast<uint4*>(&sm.g1.A[rt][sub * 16 + 8]) = v1;
    if (sub == 0) {
      float4 Pt = P.xyz4[(size_t)b * 4096 + n];
      float4 Qc = P.nq4[q];
      sm.g1.A[rt][64] = f2bf(__fsub_rn(Pt.x, Qc.x));
      sm.g1.A[rt][65] = f2bf(__fsub_rn(Pt.y, Qc.y));
      sm.g1.A[rt][66] = f2bf(__fsub_rn(Pt.z, Qc.z));
    } else if (sub == 1) {
#pragma unroll
      for (int k = 67; k < 96; ++k) sm.g1.A[rt][k] = 0;
    }
  }
  __syncthreads();
  int lane = t & 63, wid = t >> 6;
  int cl = lane & 15, rg = lane >> 4;
  int rowb = (wid << 4) + cl, ko = rg << 3;
  f32x4 acc[4] = {};
#pragma unroll
  for (int ks = 0; ks < 96; ks += 32) {
    short8 a = *reinterpret_cast<const short8*>(&sm.g1.A[rowb][ks + ko]);
#pragma unroll
    for (int nt = 0; nt < 4; ++nt) {
      short8 bb = *reinterpret_cast<const short8*>(&sm.g1.W[nt * 16 + cl][ks + ko]);
      acc[nt] = __builtin_amdgcn_mfma_f32_16x16x32_bf16(a, bb, acc[nt], 0, 0, 0);
    }
  }
#pragma unroll
  for (int nt = 0; nt < 4; ++nt) {
    int ch = nt * 16 + cl;
    float bv = P.b0[ch];
    float v0 = acc[nt][0] + bv, v1 = acc[nt][1] + bv, v2 = acc[nt][2] + bv, v3 = acc[nt][3] + bv;
    size_t gr = (size_t)w * 64 + (wid << 4) + (rg << 2);
    P.xbuf[(gr + 0) * 64 + ch] = f2bf(v0);
    P.xbuf[(gr + 1) * 64 + ch] = f2bf(v1);
    P.xbuf[(gr + 2) * 64 + ch] = f2bf(v2);
    P.xbuf[(gr + 3) * 64 + ch] = f2bf(v3);
    float s1 = (v0 + v1) + (v2 + v3);
    float s2 = (v0 * v0 + v1 * v1) + (v2 * v2 + v3 * v3);
    s1 += __shfl_xor(s1, 16); s1 += __shfl_xor(s1, 32);
    s2 += __shfl_xor(s2, 16); s2 += __shfl_xor(s2, 32);
    if (rg == 0) { sm.g1.sred[wid][0][ch] = s1; sm.g1.sred[wid][1][ch] = s2; }
  }
  __syncthreads();
  if (t < 128) {
    int ch = t & 63, wh = t >> 6;
    float v = sm.g1.sred[0][wh][ch] + sm.g1.sred[1][wh][ch] + sm.g1.sred[2][wh][ch] + sm.g1.sred[3][wh][ch];
    P.part[(size_t)w * 128 + ch * 2 + wh] = v;
  }
  __syncthreads();  // protect sm.g1 before next tile
}

// ---- mega kernel: blocks 0-15 = FPS(+incremental publish); others = prep -> ball -> gemm1 ----
__global__ __launch_bounds__(256) void k_mega(MegaP P) {
  __shared__ SmemMega sm;
  int t = threadIdx.x, blk = blockIdx.x;
  if (blk < 16) {
    __builtin_amdgcn_s_setprio(2);   // FPS is the critical path; win CU arbitration
    int b = blk;
    float px[16], py[16], pz[16], dist[16];
#pragma unroll
    for (int j = 0; j < 16; ++j) {
      int n = t + (j << 8);
      float x = P.xyz[(size_t)b * 12288 + n];
      float y = P.xyz[(size_t)b * 12288 + 4096 + n];
      float z = P.xyz[(size_t)b * 12288 + 8192 + n];
      px[j] = x; py[j] = y; pz[j] = z; dist[j] = 1e10f;
      sm.f.sp4[n] = make_float4(x, y, z, 0.f);
    }
    __syncthreads();
#pragma unroll
    for (int j = 0; j < 16; ++j) {
      asm volatile("" : "+v"(px[j]), "+v"(py[j]), "+v"(pz[j]));
    }
    unsigned nt = ~(unsigned)t;
    int far = 0;
    float cx = sm.f.sp4[0].x, cy = sm.f.sp4[0].y, cz = sm.f.sp4[0].z;
    for (int it = 0; it < 1024; ++it) {
      if (t == 0) sm.f.sfar[it] = far;
      if ((it & 15) == 0 && it != 0 && t < 16) fps_publish(P, sm, b, it - 16 + t);
      double best0 = 0.0, best1 = 0.0;
#pragma unroll
      for (int j = 0; j < 16; ++j) {
        float dx = __fsub_rn(px[j], cx);
        float dy = __fsub_rn(py[j], cy);
        float dz = __fsub_rn(pz[j], cz);
        float d  = __fadd_rn(__fadd_rn(__fmul_rn(dx, dx), __fmul_rn(dy, dy)), __fmul_rn(dz, dz));
        float nd = fminf(dist[j], d);
        dist[j] = nd;
        unsigned long long cand =
            ((unsigned long long)__builtin_bit_cast(unsigned, nd) << 32) |
            (unsigned long long)(nt - (unsigned)(j << 8));
        if (j & 1) best1 = fmax(best1, u2d(cand));
        else       best0 = fmax(best0, u2d(cand));
      }
      double best = fmax(best0, best1);
      best = dpp_max_f64<0xB1>(best);
      best = dpp_max_f64<0x4E>(best);
      best = dpp_max_f64<0x124>(best);
      best = dpp_max_f64<0x128>(best);
      int pb = it & 1;
      if ((t & 15) == 0) sm.f.scand[pb][t >> 4] = d2u(best);
      __syncthreads();   // compiler drains vmcnt here -> publish stores complete
      if ((it & 15) == 0 && it != 0 && t == 0) { __threadfence(); atomicExch(&P.prog[b], it); }
      const u64x2* cp = reinterpret_cast<const u64x2*>(sm.f.scand[pb]);
      u64x2 q0 = cp[0], q1 = cp[1], q2 = cp[2], q3 = cp[3];
      u64x2 q4 = cp[4], q5 = cp[5], q6 = cp[6], q7 = cp[7];
      double a0 = fmax(u2d(q0[0]), u2d(q0[1]));
      double a1 = fmax(u2d(q1[0]), u2d(q1[1]));
      double a2 = fmax(u2d(q2[0]), u2d(q2[1]));
      double a3 = fmax(u2d(q3[0]), u2d(q3[1]));
      double a4 = fmax(u2d(q4[0]), u2d(q4[1]));
      double a5 = fmax(u2d(q5[0]), u2d(q5[1]));
      double a6 = fmax(u2d(q6[0]), u2d(q6[1]));
      double a7 = fmax(u2d(q7[0]), u2d(q7[1]));
      double b0 = fmax(fmax(a0, a1), fmax(a2, a3));
      double b1 = fmax(fmax(a4, a5), fmax(a6, a7));
      unsigned long long bw = d2u(fmax(b0, b1));
      int n = (int)(~(unsigned)bw) & 4095;
      far = n;
      float4 c4 = sm.f.sp4[n];
      cx = c4.x; cy = c4.y; cz = c4.z;
    }
    __syncthreads();
    if (t < 16) fps_publish(P, sm, b, 1008 + t);
    __syncthreads();
    if (t == 0) { __threadfence(); atomicExch(&P.prog[b], 1024); }
    return;
  }
  // ---------------- consumers ----------------
  int ci = blk - 16, NC = P.nc;
  for (int w = ci; w < 1025; w += NC) {
    if (w == 1024) {
      for (int e = t; e < 64 * 96; e += 256) {
        int o = e / 96, k = e - o * 96;
        float v = (k < 64) ? P.w0[o * 67 + 3 + k] : ((k < 67) ? P.w0[o * 67 + (k - 64)] : 0.f);
        P.wb0[e] = f2bf(v);
      }
      for (int e = t; e < 4096; e += 256) P.wb1[e] = f2bf(P.w1[e]);
      for (int e = t; e < 8192; e += 256) P.wb2[e] = f2bf(P.w2[e]);
      __syncthreads();
      if (t == 0) { __threadfence(); atomicExch(P.wflag, 1); }
    } else {
      do_prep(w, sm, P);
      if (t == 0) { __threadfence(); atomicAdd(&P.prepcnt[w >> 6], 1); }
    }
  }
  for (int w = ci; w < 1024; w += NC) {
    int b = w >> 6, need = ((w & 63) + 1) << 4;
    if (t == 0) {
      while (atomicAdd(&P.prepcnt[b], 0) < 64) __builtin_amdgcn_s_sleep(16);
      while (atomicAdd(&P.prog[b], 0) < need) __builtin_amdgcn_s_sleep(16);
      __threadfence();   // acquire
    }
    __syncthreads();
    do_ball(w, sm, P);
    if (t == 0) { __threadfence(); atomicExch(&P.ballprog[w], 1); }
  }
  for (int w = ci; w < 8192; w += NC) {
    int idx = ((w >> 9) << 6) + ((w & 511) >> 3);
    if (t == 0) {
      while (atomicAdd(P.wflag, 0) < 1) __builtin_amdgcn_s_sleep(16);
      while (atomicAdd(&P.ballprog[idx], 0) < 1) __builtin_amdgcn_s_sleep(16);
      __threadfence();   // acquire
    }
    __syncthreads();
    do_gemm1(w, sm, P);
  }
}

// ---------------- stats partial reduce -> folded BN scale/shift (validated) ----------------
__global__ __launch_bounds__(256) void k_red(const float* __restrict__ part, int nblk, int nch,
    const float* __restrict__ gamma, const float* __restrict__ beta,
    float* __restrict__ scale, float* __restrict__ shift) {
  int c = blockIdx.x, t = threadIdx.x;
  int stride = 2 * nch;
  float s1 = 0.f, s2 = 0.f;
  for (int i = t; i < nblk; i += 256) {
    s1 += part[(size_t)i * stride + 2 * c];
    s2 += part[(size_t)i * stride + 2 * c + 1];
  }
  __shared__ float r1[256], r2[256];
  r1[t] = s1; r2[t] = s2;
  __syncthreads();
  for (int o = 128; o > 0; o >>= 1) {
    if (t < o) { r1[t] += r1[t + o]; r2[t] += r2[t + o]; }
    __syncthreads();
  }
  if (t == 0) {
    const float N = 524288.f;
    float mu = r1[0] / N;
    float var = r2[0] / N - mu * mu;
    float a = gamma[c] / sqrtf(var + 1e-5f);
    scale[c] = a;
    shift[c] = beta[c] - a * mu;
  }
}

// ---------------- Layer2 (validated) ----------------
__global__ __launch_bounds__(256) void k_gemm2(unsigned short* __restrict__ xbuf,
    const unsigned short* __restrict__ wb, const float* __restrict__ bia,
    const float* __restrict__ sc, const float* __restrict__ sh,
    float* __restrict__ part) {
  __shared__ unsigned short A[64][72];
  __shared__ unsigned short W[64][72];
  __shared__ float ssc[64], ssh[64];
  __shared__ float sred[4][2][64];
  int t = threadIdx.x, blk = blockIdx.x;
  if (t < 64) { ssc[t] = sc[t]; ssh[t] = sh[t]; }
  __syncthreads();
  for (int e = t; e < 512; e += 256) {
    int o = e >> 3, k8 = e & 7;
    *reinterpret_cast<uint4*>(&W[o][k8 * 8]) = reinterpret_cast<const uint4*>(wb)[e];
  }
  {
    int rt = t >> 2, sub = t & 3;
    size_t gr = (size_t)blk * 64 + rt;
    const uint4* src = reinterpret_cast<const uint4*>(xbuf + gr * 64 + sub * 16);
    uint4 v0 = src[0], v1 = src[1];
    unsigned wv[8] = {v0.x, v0.y, v0.z, v0.w, v1.x, v1.y, v1.z, v1.w};
    unsigned pk[8];
#pragma unroll
    for (int j = 0; j < 8; ++j) {
      int c = sub * 16 + 2 * j;
      float x0 = bf2f((unsigned short)(wv[j] & 0xffffu));
      float x1 = bf2f((unsigned short)(wv[j] >> 16));
      float a0 = fmaxf(0.f, ssc[c] * x0 + ssh[c]);
      float a1 = fmaxf(0.f, ssc[c + 1] * x1 + ssh[c + 1]);
      pk[j] = cvt_pk_bf16(a0, a1);
    }
    *reinterpret_cast<uint4*>(&A[rt][sub * 16])     = make_uint4(pk[0], pk[1], pk[2], pk[3]);
    *reinterpret_cast<uint4*>(&A[rt][sub * 16 + 8]) = make_uint4(pk[4], pk[5], pk[6], pk[7]);
  }
  __syncthreads();
  int lane = t & 63, wid = t >> 6;
  int cl = lane & 15, rg = lane >> 4;
  int rowb = (wid << 4) + cl, ko = rg << 3;
  f32x4 acc[4] = {};
#pragma unroll
  for (int ks = 0; ks < 64; ks += 32) {
    short8 a = *reinterpret_cast<const short8*>(&A[rowb][ks + ko]);
#pragma unroll
    for (int nt = 0; nt < 4; ++nt) {
      short8 bb = *reinterpret_cast<const short8*>(&W[nt * 16 + cl][ks + ko]);
      acc[nt] = __builtin_amdgcn_mfma_f32_16x16x32_bf16(a, bb, acc[nt], 0, 0, 0);
    }
  }
#pragma unroll
  for (int nt = 0; nt < 4; ++nt) {
    int ch = nt * 16 + cl;
    float bv = bia[ch];
    float v0 = acc[nt][0] + bv, v1 = acc[nt][1] + bv, v2 = acc[nt][2] + bv, v3 = acc[nt][3] + bv;
    size_t gr = (size_t)blk * 64 + (wid << 4) + (rg << 2);
    xbuf[(gr + 0) * 64 + ch] = f2bf(v0);
    xbuf[(gr + 1) * 64 + ch] = f2bf(v1);
    xbuf[(gr + 2) * 64 + ch] = f2bf(v2);
    xbuf[(gr + 3) * 64 + ch] = f2bf(v3);
    float s1 = (v0 + v1) + (v2 + v3);
    float s2 = (v0 * v0 + v1 * v1) + (v2 * v2 + v3 * v3);
    s1 += __shfl_xor(s1, 16); s1 += __shfl_xor(s1, 32);
    s2 += __shfl_xor(s2, 16); s2 += __shfl_xor(s2, 32);
    if (rg == 0) { sred[wid][0][ch] = s1; sred[wid][1][ch] = s2; }
  }
  __syncthreads();
  if (t < 128) {
    int ch = t & 63, wh = t >> 6;
    float v = sred[0][wh][ch] + sred[1][wh][ch] + sred[2][wh][ch] + sred[3][wh][ch];
    part[(size_t)blk * 128 + ch * 2 + wh] = v;
  }
}

// ---------------- Layer3 single pass (validated): GEMM + stats + per-(q,ch) max/min ----------------
__global__ __launch_bounds__(256) void k_gemm3(unsigned short* xbuf,
    const unsigned short* __restrict__ wb, const float* __restrict__ bia,
    const float* __restrict__ sc2, const float* __restrict__ sh2,
    float* __restrict__ part) {
  __shared__ unsigned short A[64][72];
  __shared__ unsigned short W[128][72];
  __shared__ float ssc[64], ssh[64];
  __shared__ float sred[4][4][128];
  int t = threadIdx.x, blk = blockIdx.x;
  if (t < 64) { ssc[t] = sc2[t]; ssh[t] = sh2[t]; }
  __syncthreads();
  for (int e = t; e < 1024; e += 256) {
    int o = e >> 3, k8 = e & 7;
    *reinterpret_cast<uint4*>(&W[o][k8 * 8]) = reinterpret_cast<const uint4*>(wb)[e];
  }
  {
    int rt = t >> 2, sub = t & 3;
    size_t gr = (size_t)blk * 64 + rt;
    const uint4* src = reinterpret_cast<const uint4*>(xbuf + gr * 64 + sub * 16);
    uint4 v0 = src[0], v1 = src[1];
    unsigned wv[8] = {v0.x, v0.y, v0.z, v0.w, v1.x, v1.y, v1.z, v1.w};
    unsigned pk[8];
#pragma unroll
    for (int j = 0; j < 8; ++j) {
      int c = sub * 16 + 2 * j;
      float x0 = bf2f((unsigned short)(wv[j] & 0xffffu));
      float x1 = bf2f((unsigned short)(wv[j] >> 16));
      float a0 = fmaxf(0.f, ssc[c] * x0 + ssh[c]);
      float a1 = fmaxf(0.f, ssc[c + 1] * x1 + ssh[c + 1]);
      pk[j] = cvt_pk_bf16(a0, a1);
    }
    *reinterpret_cast<uint4*>(&A[rt][sub * 16])     = make_uint4(pk[0], pk[1], pk[2], pk[3]);
    *reinterpret_cast<uint4*>(&A[rt][sub * 16 + 8]) = make_uint4(pk[4], pk[5], pk[6], pk[7]);
  }
  __syncthreads();
  int lane = t & 63, wid = t >> 6;
  int cl = lane & 15, rg = lane >> 4;
  int rowb = (wid << 4) + cl, ko = rg << 3;
  f32x4 acc[8] = {};
#pragma unroll
  for (int ks = 0; ks < 64; ks += 32) {
    short8 a = *reinterpret_cast<const short8*>(&A[rowb][ks + ko]);
#pragma unroll
    for (int nt = 0; nt < 8; ++nt) {
      short8 bb = *reinterpret_cast<const short8*>(&W[nt * 16 + cl][ks + ko]);
      acc[nt] = __builtin_amdgcn_mfma_f32_16x16x32_bf16(a, bb, acc[nt], 0, 0, 0);
    }
  }
#pragma unroll
  for (int nt = 0; nt < 8; ++nt) {
    int ch = nt * 16 + cl;
    float bv = bia[ch];
    float v0 = acc[nt][0] + bv, v1 = acc[nt][1] + bv, v2 = acc[nt][2] + bv, v3 = acc[nt][3] + bv;
    float s1 = (v0 + v1) + (v2 + v3);
    float s2 = (v0 * v0 + v1 * v1) + (v2 * v2 + v3 * v3);
    float mx = fmaxf(fmaxf(v0, v1), fmaxf(v2, v3));
    float mn = fminf(fminf(v0, v1), fminf(v2, v3));
    s1 += __shfl_xor(s1, 16); s1 += __shfl_xor(s1, 32);
    s2 += __shfl_xor(s2, 16); s2 += __shfl_xor(s2, 32);
    mx = fmaxf(mx, __shfl_xor(mx, 16)); mx = fmaxf(mx, __shfl_xor(mx, 32));
    mn = fminf(mn, __shfl_xor(mn, 16)); mn = fminf(mn, __shfl_xor(mn, 32));
    if (rg == 0) {
      sred[wid][0][ch] = s1; sred[wid][1][ch] = s2;
      sred[wid][2][ch] = mx; sred[wid][3][ch] = mn;
    }
  }
  __syncthreads();
  {
    int ch = t & 127, wh = t >> 7;
    part[(size_t)blk * 256 + ch * 2 + wh] =
        sred[0][wh][ch] + sred[1][wh][ch] + sred[2][wh][ch] + sred[3][wh][ch];
    float mx = fmaxf(sred[2 * wh][2][ch], sred[2 * wh + 1][2][ch]);
    float mn = fminf(sred[2 * wh][3][ch], sred[2 * wh + 1][3][ch]);
    float* mm = reinterpret_cast<float*>(xbuf) + (size_t)blk * 2048;
    mm[wh * 256 + ch]       = mx;
    mm[wh * 256 + 128 + ch] = mn;
  }
}

// ---------------- final (validated) ----------------
__global__ __launch_bounds__(256) void k_fin(const float* __restrict__ mm,
                                             const float* __restrict__ sc3,
                                             const float* __restrict__ sh3,
                                             float* __restrict__ out1) {
  __shared__ float tile[32][33];
  int t = threadIdx.x, blk = blockIdx.x;
  int b = blk >> 7, rem = blk & 127, ct = rem >> 5, st = rem & 31;
  int c0 = ct * 32, s0 = st * 32;
#pragma unroll
  for (int p = 0; p < 4; ++p) {
    int s_local = (t >> 5) + p * 8;
    int c = c0 + (t & 31);
    int q = (b << 10) + s0 + s_local;
    size_t base = (size_t)(q >> 1) * 2048 + (size_t)(q & 1) * 256;
    float mx = mm[base + c];
    float mn = mm[base + 128 + c];
    float sc = sc3[c], sh = sh3[c];
    float v = (sc >= 0.f) ? mx : mn;
    tile[t & 31][s_local] = fmaxf(0.f, sc * v + sh);
  }
  __syncthreads();
#pragma unroll
  for (int p = 0; p < 4; ++p) {
    int c = c0 + (t >> 5) + p * 8;
    int s = s0 + (t & 31);
    out1[(size_t)b * 131072 + (size_t)c * 1024 + s] = tile[(t >> 5) + p * 8][t & 31];
  }
}

extern "C" void kernel_launch(void* const* d_in, const int* in_sizes, int n_in,
                              void* d_out, int out_size, void* d_ws, size_t ws_size,
                              hipStream_t stream) {
  (void)in_sizes; (void)n_in; (void)out_size;
  const float* xyz    = (const float*)d_in[0];
  const float* points = (const float*)d_in[1];
  const float* w0  = (const float*)d_in[2];
  const float* b0  = (const float*)d_in[3];
  const float* g0  = (const float*)d_in[4];
  const float* be0 = (const float*)d_in[5];
  const float* w1  = (const float*)d_in[6];
  const float* b1  = (const float*)d_in[7];
  const float* g1  = (const float*)d_in[8];
  const float* be1 = (const float*)d_in[9];
  const float* w2  = (const float*)d_in[10];
  const float* b2  = (const float*)d_in[11];
  const float* g2  = (const float*)d_in[12];
  const float* be2 = (const float*)d_in[13];
  float* out  = (float*)d_out;
  float* out0 = out;
  float* out1 = out + 49152;
  float* out2 = out + 49152 + 2097152;
  char* ws = (char*)d_ws;
  const size_t OFF_PT    = 0;         // 8388608
  const size_t OFF_XYZ4  = 8388608;   // 1048576
  const size_t OFF_NQ4   = 9437184;   // 262144
  const size_t OFF_FPS   = 9699328;   // 65536
  const size_t OFF_BALL  = 9764864;   // 2097152
  const size_t OFF_XBUF  = 11862016;  // 67108864 (tail-aliased as max/min store by k_gemm3)
  const size_t OFF_PART  = 78970880;  // 8388608
  const size_t OFF_SC    = 87359488;  // 4096
  const size_t OFF_WB    = 87363584;  // 36864
  const size_t OFF_FLAGS = 87400448;  // 8192
  const size_t NEED      = 87408640;
  if (ws_size < NEED) return;
  unsigned short* pT   = (unsigned short*)(ws + OFF_PT);
  float4* xyz4 = (float4*)(ws + OFF_XYZ4);
  float4* nq4  = (float4*)(ws + OFF_NQ4);
  int* fpsidx  = (int*)(ws + OFF_FPS);
  int* ballidx = (int*)(ws + OFF_BALL);
  unsigned short* xbuf = (unsigned short*)(ws + OFF_XBUF);
  float* part  = (float*)(ws + OFF_PART);
  float* scb   = (float*)(ws + OFF_SC);
  float *sc1 = scb, *sh1 = scb + 128, *sc2 = scb + 256, *sh2 = scb + 384,
        *sc3 = scb + 512, *sh3 = scb + 640;
  unsigned short* wb0 = (unsigned short*)(ws + OFF_WB);
  unsigned short* wb1 = wb0 + 6144;
  unsigned short* wb2 = wb1 + 4096;
  int* flags = (int*)(ws + OFF_FLAGS);
  int* prog = flags;            // [16]
  int* prepcnt = flags + 16;    // [16]
  int* wflag = flags + 32;      // [1]
  int* ballprog = flags + 64;   // [1024]

  hipMemsetAsync(ws + OFF_FLAGS, 0, 8192, stream);

  int nb = 0;
  hipOccupancyMaxActiveBlocksPerMultiprocessor(&nb, reinterpret_cast<const void*>(k_mega), 256, 0);
  int G = nb * 256;
  if (G > 512) G = 512;
  if (G < 32) G = 32;   // 32 blocks are trivially co-resident on 256 CUs

  MegaP P;
  P.xyz = xyz; P.points = points;
  P.out0 = out0; P.out2 = out2;
  P.fpsidx = fpsidx; P.nq4 = nq4;
  P.pT = pT; P.xyz4 = xyz4;
  P.w0 = w0; P.w1 = w1; P.w2 = w2;
  P.wb0 = wb0; P.wb1 = wb1; P.wb2 = wb2;
  P.b0 = b0;
  P.xbuf = xbuf; P.part = part;
  P.bidx = ballidx;
  P.prog = prog; P.prepcnt = prepcnt; P.wflag = wflag; P.ballprog = ballprog;
  P.nc = G - 16;
  void* args[] = { &P };
  hipLaunchCooperativeKernel(reinterpret_cast<void*>(k_mega), dim3(G), dim3(256), args, 0, stream);

  k_red<<<64, 256, 0, stream>>>(part, 8192, 64, g0, be0, sc1, sh1);
  k_gemm2<<<8192, 256, 0, stream>>>(xbuf, wb1, b1, sc1, sh1, part);
  k_red<<<64, 256, 0, stream>>>(part, 8192, 64, g1, be1, sc2, sh2);
  k_gemm3<<<8192, 256, 0, stream>>>(xbuf, wb2, b2, sc2, sh2, part);
  k_red<<<128, 256, 0, stream>>>(part, 8192, 128, g2, be2, sc3, sh3);
  k_fin<<<2048, 256, 0, stream>>>((const float*)xbuf, sc3, sh3, out1);
}

// Round 10
// 1134.594 us; speedup vs baseline: 1.0651x; 1.0651x over previous
//
#include <hip/hip_runtime.h>
#include <hip/hip_cooperative_groups.h>

namespace cg = cooperative_groups;

using f32x4  = __attribute__((ext_vector_type(4))) float;
using short8 = __attribute__((ext_vector_type(8))) short;
using u64x2  = __attribute__((ext_vector_type(2))) unsigned long long;

__device__ __forceinline__ unsigned short f2bf(float f) {
  unsigned u = __builtin_bit_cast(unsigned, f);
  u = (u + 0x7FFFu + ((u >> 16) & 1u)) >> 16;
  return (unsigned short)u;
}
__device__ __forceinline__ float bf2f(unsigned short s) {
  return __builtin_bit_cast(float, ((unsigned)s) << 16);
}
__device__ __forceinline__ double u2d(unsigned long long u) {
  return __builtin_bit_cast(double, u);
}
__device__ __forceinline__ unsigned long long d2u(double d) {
  return __builtin_bit_cast(unsigned long long, d);
}
__device__ __forceinline__ unsigned cvt_pk_bf16(float lo, float hi) {
  unsigned r;
  asm("v_cvt_pk_bf16_f32 %0, %1, %2" : "=v"(r) : "v"(lo), "v"(hi));
  return r;
}
// Agent-scope (device) atomics: coherent at MALL, no L2 invalidation storms.
__device__ __forceinline__ void astore(int* p, int v) {
  __hip_atomic_store(p, v, __ATOMIC_RELAXED, __HIP_MEMORY_SCOPE_AGENT);
}
__device__ __forceinline__ int aload(const int* p) {
  return __hip_atomic_load(p, __ATOMIC_RELAXED, __HIP_MEMORY_SCOPE_AGENT);
}

// DPP f64 max (reduction; non-receiving lanes get 0 which is < any candidate).
template <int CTRL>
__device__ __forceinline__ double dpp_max_f64(double best) {
  unsigned long long u = d2u(best);
  int lo32 = (int)(unsigned)u;
  int hi32 = (int)(unsigned)(u >> 32);
  int plo = __builtin_amdgcn_update_dpp(0, lo32, CTRL, 0xF, 0xF, true);
  int phi = __builtin_amdgcn_update_dpp(0, hi32, CTRL, 0xF, 0xF, true);
  unsigned long long p =
      ((unsigned long long)(unsigned)phi << 32) | (unsigned long long)(unsigned)plo;
  return fmax(best, u2d(p));
}
// DPP f64 min (bound_ctrl=false: non-receiving lanes keep self).
template <int CTRL>
__device__ __forceinline__ double dpp_min_f64(double v) {
  unsigned long long u = d2u(v);
  int lo32 = (int)(unsigned)u;
  int hi32 = (int)(unsigned)(u >> 32);
  int plo = __builtin_amdgcn_update_dpp(lo32, lo32, CTRL, 0xF, 0xF, false);
  int phi = __builtin_amdgcn_update_dpp(hi32, hi32, CTRL, 0xF, 0xF, false);
  unsigned long long p =
      ((unsigned long long)(unsigned)phi << 32) | (unsigned long long)(unsigned)plo;
  return fmin(v, u2d(p));
}

#define BCAP 384

union __align__(16) SmemMega {
  struct { float4 sp4[4096]; unsigned long long scand[2][16]; int sfar[1024]; } f; // FPS
  float tile[64][65];                                                              // prep
  struct { float4 sp[4096]; unsigned long long spk[4][BCAP]; } bq;                 // ball
  struct { unsigned short A[64][104]; unsigned short W[64][104]; float sred[4][2][64]; } g1;
};

struct MegaP {
  const float* xyz; const float* points;
  float* out0; float* out2;
  int* fpsidx;
  unsigned short* pT; float4* xyz4;
  const float* w0; const float* w1; const float* w2;
  unsigned short* wb0; unsigned short* wb1; unsigned short* wb2;
  const float* b0;
  unsigned short* xbuf; float* part;
  int* bidx;
  int* prog; int* ballprog;
  int nc;
};

// ---- publish one FPS slot (identical numerics; fpsidx via coherent atomic) ----
__device__ __forceinline__ void fps_publish(const MegaP& P, SmemMega& sm, int b, int k) {
  int fr = sm.f.sfar[k];
  float4 p = sm.f.sp4[fr];
  astore(&P.fpsidx[(b << 10) + k], fr);
  P.out2[(b << 10) + k] = (float)fr;
  P.out0[(size_t)b * 3072 + k]        = p.x;
  P.out0[(size_t)b * 3072 + 1024 + k] = p.y;
  P.out0[(size_t)b * 3072 + 2048 + k] = p.z;
}

// ---- prep tile (validated body) ----
__device__ __forceinline__ void do_prep(int pb, SmemMega& sm, const MegaP& P) {
  int t = threadIdx.x;
  int b = pb >> 6, n0 = (pb & 63) << 6;
#pragma unroll
  for (int p = 0; p < 16; ++p) {
    int c = p * 4 + (t >> 6);
    sm.tile[c][t & 63] = P.points[(size_t)b * 262144 + (size_t)c * 4096 + n0 + (t & 63)];
  }
  if (t < 64) {
    int n = n0 + t;
    float x = P.xyz[(size_t)b * 12288 + n];
    float y = P.xyz[(size_t)b * 12288 + 4096 + n];
    float z = P.xyz[(size_t)b * 12288 + 8192 + n];
    float ps = __fadd_rn(__fadd_rn(__fmul_rn(x, x), __fmul_rn(y, y)), __fmul_rn(z, z));
    P.xyz4[(size_t)b * 4096 + n] = make_float4(x, y, z, ps);
  }
  __syncthreads();
  int nl = t >> 2, coff = (t & 3) * 16;
  unsigned v[8];
#pragma unroll
  for (int j = 0; j < 8; ++j)
    v[j] = cvt_pk_bf16(sm.tile[coff + 2 * j][nl], sm.tile[coff + 2 * j + 1][nl]);
  uint4* dst = reinterpret_cast<uint4*>(P.pT + ((size_t)b * 4096 + n0 + nl) * 64 + coff);
  dst[0] = make_uint4(v[0], v[1], v[2], v[3]);
  dst[1] = make_uint4(v[4], v[5], v[6], v[7]);
  __syncthreads();  // protect sm.tile before next loop tile
}

// ---- ball tile (validated body; fpsidx/bidx via atomics) ----
__device__ __forceinline__ void do_ball(int w, SmemMega& sm, const MegaP& P) {
  const unsigned long long INVP = 0x7149F2CAFFFFFFFFull;
  int t = threadIdx.x;
  int b = w >> 6;
  for (int i = t; i < 4096; i += 256) sm.bq.sp[i] = P.xyz4[(size_t)b * 4096 + i];
  __syncthreads();
  int lane = t & 63, wid = t >> 6;
  for (int r = 0; r < 4; ++r) {
    int q = w * 16 + r * 4 + wid;
    int qi = aload(&P.fpsidx[q]);
    float4 Q = sm.bq.sp[qi];
    float qx = Q.x, qy = Q.y, qz = Q.z, qs = Q.w;
    int cnt = 0;
    for (int i = 0; i < 64; ++i) {
      int n = (i << 6) + lane;
      float4 Pp = sm.bq.sp[n];
      float dot = __fadd_rn(__fadd_rn(__fmul_rn(qx, Pp.x), __fmul_rn(qy, Pp.y)), __fmul_rn(qz, Pp.z));
      float d   = __fadd_rn(__fadd_rn(__fmul_rn(-2.f, dot), qs), Pp.w);
      bool in = (d <= 0.04f);
      unsigned long long m = __ballot(in);
      int pos = cnt + (int)__popcll(m & ((1ull << lane) - 1ull));
      if (in && pos < BCAP)
        sm.bq.spk[wid][pos] = ((unsigned long long)__builtin_bit_cast(unsigned, d) << 32) | (unsigned)n;
      cnt += (int)__popcll(m);
    }
    if (cnt > BCAP) cnt = BCAP;
    double c0, c1, c2, c3, c4, c5;
    {
      int s0 = lane, s1 = lane + 64, s2 = lane + 128, s3 = lane + 192, s4 = lane + 256, s5 = lane + 320;
      c0 = (s0 < cnt) ? u2d(sm.bq.spk[wid][s0]) : u2d(INVP);
      c1 = (s1 < cnt) ? u2d(sm.bq.spk[wid][s1]) : u2d(INVP);
      c2 = (s2 < cnt) ? u2d(sm.bq.spk[wid][s2]) : u2d(INVP);
      c3 = (s3 < cnt) ? u2d(sm.bq.spk[wid][s3]) : u2d(INVP);
      c4 = (s4 < cnt) ? u2d(sm.bq.spk[wid][s4]) : u2d(INVP);
      c5 = (s5 < cnt) ? u2d(sm.bq.spk[wid][s5]) : u2d(INVP);
    }
#define CE(a, b) { double mn_ = fmin(a, b), mx_ = fmax(a, b); a = mn_; b = mx_; }
    CE(c0, c1);
    CE(c1, c2); CE(c0, c1);
    CE(c2, c3); CE(c1, c2); CE(c0, c1);
    CE(c3, c4); CE(c2, c3); CE(c1, c2); CE(c0, c1);
    CE(c4, c5); CE(c3, c4); CE(c2, c3); CE(c1, c2); CE(c0, c1);
#undef CE
    int firstI = 0;
#pragma unroll 1
    for (int rr = 0; rr < 32; ++rr) {
      double h = c0;
      h = dpp_min_f64<0xB1>(h);
      h = dpp_min_f64<0x4E>(h);
      h = dpp_min_f64<0x124>(h);
      h = dpp_min_f64<0x128>(h);
      unsigned long long hu = d2u(h);
      int lo = (int)(unsigned)hu, hi = (int)(unsigned)(hu >> 32);
      unsigned long long r0 = ((unsigned long long)(unsigned)__builtin_amdgcn_readlane(hi, 0)  << 32) | (unsigned)__builtin_amdgcn_readlane(lo, 0);
      unsigned long long r1 = ((unsigned long long)(unsigned)__builtin_amdgcn_readlane(hi, 16) << 32) | (unsigned)__builtin_amdgcn_readlane(lo, 16);
      unsigned long long r2 = ((unsigned long long)(unsigned)__builtin_amdgcn_readlane(hi, 32) << 32) | (unsigned)__builtin_amdgcn_readlane(lo, 32);
      unsigned long long r3 = ((unsigned long long)(unsigned)__builtin_amdgcn_readlane(hi, 48) << 32) | (unsigned)__builtin_amdgcn_readlane(lo, 48);
      double ww = fmin(fmin(u2d(r0), u2d(r1)), fmin(u2d(r2), u2d(r3)));
      unsigned long long wu = d2u(ww);
      int wi = (int)(unsigned)wu;
      if (rr == 0) firstI = wi;
      int outv = (wu < INVP) ? wi : firstI;
      if (lane == 0) astore(&P.bidx[(size_t)q * 32 + rr], outv);
      if (d2u(c0) == wu) { c0 = c1; c1 = c2; c2 = c3; c3 = c4; c4 = c5; c5 = u2d(INVP); }
    }
  }
  __syncthreads();  // drains vmcnt (bidx stores) before ballprog flag; protects sm.bq
}

// ---- gemm1 tile (validated body; bidx/fpsidx via atomics; Qc from xyz4) ----
__device__ __forceinline__ void do_gemm1(int w, SmemMega& sm, const MegaP& P) {
  int t = threadIdx.x;
  int b = w >> 9;
  for (int e = t; e < 768; e += 256) {
    int o = e / 12, k8 = e - o * 12;
    *reinterpret_cast<uint4*>(&sm.g1.W[o][k8 * 8]) = reinterpret_cast<const uint4*>(P.wb0)[e];
  }
  {
    int rt = t >> 2, sub = t & 3;
    int q = (w << 1) + (rt >> 5);
    int n = aload(&P.bidx[(size_t)q * 32 + (rt & 31)]);
    const uint4* src = reinterpret_cast<const uint4*>(P.pT + ((size_t)(b * 4096 + n)) * 64 + sub * 16);
    uint4 v0 = src[0], v1 = src[1];
    *reinterpret_cast<uint4*>(&sm.g1.A[rt][sub * 16])     = v0;
    *reinterpret_cast<uint4*>(&sm.g1.A[rt][sub * 16 + 8]) = v1;
    if (sub == 0) {
      float4 Pt = P.xyz4[(size_t)b * 4096 + n];
      int qi = aload(&P.fpsidx[q]);
      float4 Qc = P.xyz4[(size_t)b * 4096 + qi];   // bitwise == old nq4[q].xyz
      sm.g1.A[rt][64] = f2bf(__fsub_rn(Pt.x, Qc.x));
      sm.g1.A[rt][65] = f2bf(__fsub_rn(Pt.y, Qc.y));
      sm.g1.A[rt][66] = f2bf(__fsub_rn(Pt.z, Qc.z));
    } else if (sub == 1) {
#pragma unroll
      for (int k = 67; k < 96; ++k) sm.g1.A[rt][k] = 0;
    }
  }
  __syncthreads();
  int lane = t & 63, wid = t >> 6;
  int cl = lane & 15, rg = lane >> 4;
  int rowb = (wid << 4) + cl, ko = rg << 3;
  f32x4 acc[4] = {};
#pragma unroll
  for (int ks = 0; ks < 96; ks += 32) {
    short8 a = *reinterpret_cast<const short8*>(&sm.g1.A[rowb][ks + ko]);
#pragma unroll
    for (int nt = 0; nt < 4; ++nt) {
      short8 bb = *reinterpret_cast<const short8*>(&sm.g1.W[nt * 16 + cl][ks + ko]);
      acc[nt] = __builtin_amdgcn_mfma_f32_16x16x32_bf16(a, bb, acc[nt], 0, 0, 0);
    }
  }
#pragma unroll
  for (int nt = 0; nt < 4; ++nt) {
    int ch = nt * 16 + cl;
    float bv = P.b0[ch];
    float v0 = acc[nt][0] + bv, v1 = acc[nt][1] + bv, v2 = acc[nt][2] + bv, v3 = acc[nt][3] + bv;
    size_t gr = (size_t)w * 64 + (wid << 4) + (rg << 2);
    P.xbuf[(gr + 0) * 64 + ch] = f2bf(v0);
    P.xbuf[(gr + 1) * 64 + ch] = f2bf(v1);
    P.xbuf[(gr + 2) * 64 + ch] = f2bf(v2);
    P.xbuf[(gr + 3) * 64 + ch] = f2bf(v3);
    float s1 = (v0 + v1) + (v2 + v3);
    float s2 = (v0 * v0 + v1 * v1) + (v2 * v2 + v3 * v3);
    s1 += __shfl_xor(s1, 16); s1 += __shfl_xor(s1, 32);
    s2 += __shfl_xor(s2, 16); s2 += __shfl_xor(s2, 32);
    if (rg == 0) { sm.g1.sred[wid][0][ch] = s1; sm.g1.sred[wid][1][ch] = s2; }
  }
  __syncthreads();
  if (t < 128) {
    int ch = t & 63, wh = t >> 6;
    float v = sm.g1.sred[0][wh][ch] + sm.g1.sred[1][wh][ch] + sm.g1.sred[2][wh][ch] + sm.g1.sred[3][wh][ch];
    P.part[(size_t)w * 128 + ch * 2 + wh] = v;
  }
  __syncthreads();  // protect sm.g1 before next tile
}

// ---- mega kernel: blocks 0-15 = FPS(+incremental publish); others = prep / ball / gemm1.
// One grid.sync() after prep+weights replaces all per-tile fences (static data visibility);
// dynamic handoff (fpsidx/bidx/prog/ballprog) rides agent-scope atomics (no cache invalidates).
__global__ __launch_bounds__(256) void k_mega(MegaP P) {
  __shared__ SmemMega sm;
  int t = threadIdx.x, blk = blockIdx.x;
  if (blk < 16) {
    __builtin_amdgcn_s_setprio(2);   // FPS is the critical path
    int b = blk;
    float px[16], py[16], pz[16], dist[16];
#pragma unroll
    for (int j = 0; j < 16; ++j) {
      int n = t + (j << 8);
      float x = P.xyz[(size_t)b * 12288 + n];
      float y = P.xyz[(size_t)b * 12288 + 4096 + n];
      float z = P.xyz[(size_t)b * 12288 + 8192 + n];
      px[j] = x; py[j] = y; pz[j] = z; dist[j] = 1e10f;
      sm.f.sp4[n] = make_float4(x, y, z, 0.f);
    }
    __syncthreads();
    cg::this_grid().sync();
#pragma unroll
    for (int j = 0; j < 16; ++j) {
      asm volatile("" : "+v"(px[j]), "+v"(py[j]), "+v"(pz[j]));
    }
    unsigned nt = ~(unsigned)t;
    int far = 0;
    float cx = sm.f.sp4[0].x, cy = sm.f.sp4[0].y, cz = sm.f.sp4[0].z;
    for (int it = 0; it < 1024; ++it) {
      if (t == 0) sm.f.sfar[it] = far;
      if ((it & 15) == 0 && it != 0 && t < 16) fps_publish(P, sm, b, it - 16 + t);
      double best0 = 0.0, best1 = 0.0;
#pragma unroll
      for (int j = 0; j < 16; ++j) {
        float dx = __fsub_rn(px[j], cx);
        float dy = __fsub_rn(py[j], cy);
        float dz = __fsub_rn(pz[j], cz);
        float d  = __fadd_rn(__fadd_rn(__fmul_rn(dx, dx), __fmul_rn(dy, dy)), __fmul_rn(dz, dz));
        float nd = fminf(dist[j], d);
        dist[j] = nd;
        unsigned long long cand =
            ((unsigned long long)__builtin_bit_cast(unsigned, nd) << 32) |
            (unsigned long long)(nt - (unsigned)(j << 8));
        if (j & 1) best1 = fmax(best1, u2d(cand));
        else       best0 = fmax(best0, u2d(cand));
      }
      double best = fmax(best0, best1);
      best = dpp_max_f64<0xB1>(best);
      best = dpp_max_f64<0x4E>(best);
      best = dpp_max_f64<0x124>(best);
      best = dpp_max_f64<0x128>(best);
      int pb = it & 1;
      if ((t & 15) == 0) sm.f.scand[pb][t >> 4] = d2u(best);
      __syncthreads();   // drains vmcnt -> publish atomics complete before prog store
      if ((it & 15) == 0 && it != 0 && t == 0) astore(&P.prog[b], it);
      const u64x2* cp = reinterpret_cast<const u64x2*>(sm.f.scand[pb]);
      u64x2 q0 = cp[0], q1 = cp[1], q2 = cp[2], q3 = cp[3];
      u64x2 q4 = cp[4], q5 = cp[5], q6 = cp[6], q7 = cp[7];
      double a0 = fmax(u2d(q0[0]), u2d(q0[1]));
      double a1 = fmax(u2d(q1[0]), u2d(q1[1]));
      double a2 = fmax(u2d(q2[0]), u2d(q2[1]));
      double a3 = fmax(u2d(q3[0]), u2d(q3[1]));
      double a4 = fmax(u2d(q4[0]), u2d(q4[1]));
      double a5 = fmax(u2d(q5[0]), u2d(q5[1]));
      double a6 = fmax(u2d(q6[0]), u2d(q6[1]));
      double a7 = fmax(u2d(q7[0]), u2d(q7[1]));
      double b0 = fmax(fmax(a0, a1), fmax(a2, a3));
      double b1 = fmax(fmax(a4, a5), fmax(a6, a7));
      unsigned long long bw = d2u(fmax(b0, b1));
      int n = (int)(~(unsigned)bw) & 4095;
      far = n;
      float4 c4 = sm.f.sp4[n];
      cx = c4.x; cy = c4.y; cz = c4.z;
    }
    __syncthreads();
    if (t < 16) fps_publish(P, sm, b, 1008 + t);
    __syncthreads();   // drains vmcnt for the final publishes
    if (t == 0) astore(&P.prog[b], 1024);
    return;
  }
  // ---------------- consumers ----------------
  int ci = blk - 16, NC = P.nc;
  for (int w = ci; w < 1025; w += NC) {
    if (w == 1024) {
      for (int e = t; e < 64 * 96; e += 256) {
        int o = e / 96, k = e - o * 96;
        float v = (k < 64) ? P.w0[o * 67 + 3 + k] : ((k < 67) ? P.w0[o * 67 + (k - 64)] : 0.f);
        P.wb0[e] = f2bf(v);
      }
      for (int e = t; e < 4096; e += 256) P.wb1[e] = f2bf(P.w1[e]);
      for (int e = t; e < 8192; e += 256) P.wb2[e] = f2bf(P.w2[e]);
    } else {
      do_prep(w, sm, P);
    }
  }
  cg::this_grid().sync();   // xyz4/pT/wb* now visible to all XCDs; no per-tile fences
  for (int w = ci; w < 1024; w += NC) {
    int b = w >> 6, need = ((w & 63) + 1) << 4;
    if (t == 0) {
      while (aload(&P.prog[b]) < need) __builtin_amdgcn_s_sleep(16);
    }
    __syncthreads();
    do_ball(w, sm, P);
    if (t == 0) astore(&P.ballprog[w], 1);
  }
  for (int w = ci; w < 8192; w += NC) {
    int idx = ((w >> 9) << 6) + ((w & 511) >> 3);
    if (t == 0) {
      while (aload(&P.ballprog[idx]) < 1) __builtin_amdgcn_s_sleep(16);
    }
    __syncthreads();
    do_gemm1(w, sm, P);
  }
}

// ---------------- stats partial reduce -> folded BN scale/shift (validated) ----------------
__global__ __launch_bounds__(256) void k_red(const float* __restrict__ part, int nblk, int nch,
    const float* __restrict__ gamma, const float* __restrict__ beta,
    float* __restrict__ scale, float* __restrict__ shift) {
  int c = blockIdx.x, t = threadIdx.x;
  int stride = 2 * nch;
  float s1 = 0.f, s2 = 0.f;
  for (int i = t; i < nblk; i += 256) {
    s1 += part[(size_t)i * stride + 2 * c];
    s2 += part[(size_t)i * stride + 2 * c + 1];
  }
  __shared__ float r1[256], r2[256];
  r1[t] = s1; r2[t] = s2;
  __syncthreads();
  for (int o = 128; o > 0; o >>= 1) {
    if (t < o) { r1[t] += r1[t + o]; r2[t] += r2[t + o]; }
    __syncthreads();
  }
  if (t == 0) {
    const float N = 524288.f;
    float mu = r1[0] / N;
    float var = r2[0] / N - mu * mu;
    float a = gamma[c] / sqrtf(var + 1e-5f);
    scale[c] = a;
    shift[c] = beta[c] - a * mu;
  }
}

// ---------------- Layer2 (validated) ----------------
__global__ __launch_bounds__(256) void k_gemm2(unsigned short* __restrict__ xbuf,
    const unsigned short* __restrict__ wb, const float* __restrict__ bia,
    const float* __restrict__ sc, const float* __restrict__ sh,
    float* __restrict__ part) {
  __shared__ unsigned short A[64][72];
  __shared__ unsigned short W[64][72];
  __shared__ float ssc[64], ssh[64];
  __shared__ float sred[4][2][64];
  int t = threadIdx.x, blk = blockIdx.x;
  if (t < 64) { ssc[t] = sc[t]; ssh[t] = sh[t]; }
  __syncthreads();
  for (int e = t; e < 512; e += 256) {
    int o = e >> 3, k8 = e & 7;
    *reinterpret_cast<uint4*>(&W[o][k8 * 8]) = reinterpret_cast<const uint4*>(wb)[e];
  }
  {
    int rt = t >> 2, sub = t & 3;
    size_t gr = (size_t)blk * 64 + rt;
    const uint4* src = reinterpret_cast<const uint4*>(xbuf + gr * 64 + sub * 16);
    uint4 v0 = src[0], v1 = src[1];
    unsigned wv[8] = {v0.x, v0.y, v0.z, v0.w, v1.x, v1.y, v1.z, v1.w};
    unsigned pk[8];
#pragma unroll
    for (int j = 0; j < 8; ++j) {
      int c = sub * 16 + 2 * j;
      float x0 = bf2f((unsigned short)(wv[j] & 0xffffu));
      float x1 = bf2f((unsigned short)(wv[j] >> 16));
      float a0 = fmaxf(0.f, ssc[c] * x0 + ssh[c]);
      float a1 = fmaxf(0.f, ssc[c + 1] * x1 + ssh[c + 1]);
      pk[j] = cvt_pk_bf16(a0, a1);
    }
    *reinterpret_cast<uint4*>(&A[rt][sub * 16])     = make_uint4(pk[0], pk[1], pk[2], pk[3]);
    *reinterpret_cast<uint4*>(&A[rt][sub * 16 + 8]) = make_uint4(pk[4], pk[5], pk[6], pk[7]);
  }
  __syncthreads();
  int lane = t & 63, wid = t >> 6;
  int cl = lane & 15, rg = lane >> 4;
  int rowb = (wid << 4) + cl, ko = rg << 3;
  f32x4 acc[4] = {};
#pragma unroll
  for (int ks = 0; ks < 64; ks += 32) {
    short8 a = *reinterpret_cast<const short8*>(&A[rowb][ks + ko]);
#pragma unroll
    for (int nt = 0; nt < 4; ++nt) {
      short8 bb = *reinterpret_cast<const short8*>(&W[nt * 16 + cl][ks + ko]);
      acc[nt] = __builtin_amdgcn_mfma_f32_16x16x32_bf16(a, bb, acc[nt], 0, 0, 0);
    }
  }
#pragma unroll
  for (int nt = 0; nt < 4; ++nt) {
    int ch = nt * 16 + cl;
    float bv = bia[ch];
    float v0 = acc[nt][0] + bv, v1 = acc[nt][1] + bv, v2 = acc[nt][2] + bv, v3 = acc[nt][3] + bv;
    size_t gr = (size_t)blk * 64 + (wid << 4) + (rg << 2);
    xbuf[(gr + 0) * 64 + ch] = f2bf(v0);
    xbuf[(gr + 1) * 64 + ch] = f2bf(v1);
    xbuf[(gr + 2) * 64 + ch] = f2bf(v2);
    xbuf[(gr + 3) * 64 + ch] = f2bf(v3);
    float s1 = (v0 + v1) + (v2 + v3);
    float s2 = (v0 * v0 + v1 * v1) + (v2 * v2 + v3 * v3);
    s1 += __shfl_xor(s1, 16); s1 += __shfl_xor(s1, 32);
    s2 += __shfl_xor(s2, 16); s2 += __shfl_xor(s2, 32);
    if (rg == 0) { sred[wid][0][ch] = s1; sred[wid][1][ch] = s2; }
  }
  __syncthreads();
  if (t < 128) {
    int ch = t & 63, wh = t >> 6;
    float v = sred[0][wh][ch] + sred[1][wh][ch] + sred[2][wh][ch] + sred[3][wh][ch];
    part[(size_t)blk * 128 + ch * 2 + wh] = v;
  }
}

// ---------------- Layer3 single pass (validated): GEMM + stats + per-(q,ch) max/min ----------------
__global__ __launch_bounds__(256) void k_gemm3(unsigned short* xbuf,
    const unsigned short* __restrict__ wb, const float* __restrict__ bia,
    const float* __restrict__ sc2, const float* __restrict__ sh2,
    float* __restrict__ part) {
  __shared__ unsigned short A[64][72];
  __shared__ unsigned short W[128][72];
  __shared__ float ssc[64], ssh[64];
  __shared__ float sred[4][4][128];
  int t = threadIdx.x, blk = blockIdx.x;
  if (t < 64) { ssc[t] = sc2[t]; ssh[t] = sh2[t]; }
  __syncthreads();
  for (int e = t; e < 1024; e += 256) {
    int o = e >> 3, k8 = e & 7;
    *reinterpret_cast<uint4*>(&W[o][k8 * 8]) = reinterpret_cast<const uint4*>(wb)[e];
  }
  {
    int rt = t >> 2, sub = t & 3;
    size_t gr = (size_t)blk * 64 + rt;
    const uint4* src = reinterpret_cast<const uint4*>(xbuf + gr * 64 + sub * 16);
    uint4 v0 = src[0], v1 = src[1];
    unsigned wv[8] = {v0.x, v0.y, v0.z, v0.w, v1.x, v1.y, v1.z, v1.w};
    unsigned pk[8];
#pragma unroll
    for (int j = 0; j < 8; ++j) {
      int c = sub * 16 + 2 * j;
      float x0 = bf2f((unsigned short)(wv[j] & 0xffffu));
      float x1 = bf2f((unsigned short)(wv[j] >> 16));
      float a0 = fmaxf(0.f, ssc[c] * x0 + ssh[c]);
      float a1 = fmaxf(0.f, ssc[c + 1] * x1 + ssh[c + 1]);
      pk[j] = cvt_pk_bf16(a0, a1);
    }
    *reinterpret_cast<uint4*>(&A[rt][sub * 16])     = make_uint4(pk[0], pk[1], pk[2], pk[3]);
    *reinterpret_cast<uint4*>(&A[rt][sub * 16 + 8]) = make_uint4(pk[4], pk[5], pk[6], pk[7]);
  }
  __syncthreads();
  int lane = t & 63, wid = t >> 6;
  int cl = lane & 15, rg = lane >> 4;
  int rowb = (wid << 4) + cl, ko = rg << 3;
  f32x4 acc[8] = {};
#pragma unroll
  for (int ks = 0; ks < 64; ks += 32) {
    short8 a = *reinterpret_cast<const short8*>(&A[rowb][ks + ko]);
#pragma unroll
    for (int nt = 0; nt < 8; ++nt) {
      short8 bb = *reinterpret_cast<const short8*>(&W[nt * 16 + cl][ks + ko]);
      acc[nt] = __builtin_amdgcn_mfma_f32_16x16x32_bf16(a, bb, acc[nt], 0, 0, 0);
    }
  }
#pragma unroll
  for (int nt = 0; nt < 8; ++nt) {
    int ch = nt * 16 + cl;
    float bv = bia[ch];
    float v0 = acc[nt][0] + bv, v1 = acc[nt][1] + bv, v2 = acc[nt][2] + bv, v3 = acc[nt][3] + bv;
    float s1 = (v0 + v1) + (v2 + v3);
    float s2 = (v0 * v0 + v1 * v1) + (v2 * v2 + v3 * v3);
    float mx = fmaxf(fmaxf(v0, v1), fmaxf(v2, v3));
    float mn = fminf(fminf(v0, v1), fminf(v2, v3));
    s1 += __shfl_xor(s1, 16); s1 += __shfl_xor(s1, 32);
    s2 += __shfl_xor(s2, 16); s2 += __shfl_xor(s2, 32);
    mx = fmaxf(mx, __shfl_xor(mx, 16)); mx = fmaxf(mx, __shfl_xor(mx, 32));
    mn = fminf(mn, __shfl_xor(mn, 16)); mn = fminf(mn, __shfl_xor(mn, 32));
    if (rg == 0) {
      sred[wid][0][ch] = s1; sred[wid][1][ch] = s2;
      sred[wid][2][ch] = mx; sred[wid][3][ch] = mn;
    }
  }
  __syncthreads();
  {
    int ch = t & 127, wh = t >> 7;
    part[(size_t)blk * 256 + ch * 2 + wh] =
        sred[0][wh][ch] + sred[1][wh][ch] + sred[2][wh][ch] + sred[3][wh][ch];
    float mx = fmaxf(sred[2 * wh][2][ch], sred[2 * wh + 1][2][ch]);
    float mn = fminf(sred[2 * wh][3][ch], sred[2 * wh + 1][3][ch]);
    float* mm = reinterpret_cast<float*>(xbuf) + (size_t)blk * 2048;
    mm[wh * 256 + ch]       = mx;
    mm[wh * 256 + 128 + ch] = mn;
  }
}

// ---------------- final (validated) ----------------
__global__ __launch_bounds__(256) void k_fin(const float* __restrict__ mm,
                                             const float* __restrict__ sc3,
                                             const float* __restrict__ sh3,
                                             float* __restrict__ out1) {
  __shared__ float tile[32][33];
  int t = threadIdx.x, blk = blockIdx.x;
  int b = blk >> 7, rem = blk & 127, ct = rem >> 5, st = rem & 31;
  int c0 = ct * 32, s0 = st * 32;
#pragma unroll
  for (int p = 0; p < 4; ++p) {
    int s_local = (t >> 5) + p * 8;
    int c = c0 + (t & 31);
    int q = (b << 10) + s0 + s_local;
    size_t base = (size_t)(q >> 1) * 2048 + (size_t)(q & 1) * 256;
    float mx = mm[base + c];
    float mn = mm[base + 128 + c];
    float sc = sc3[c], sh = sh3[c];
    float v = (sc >= 0.f) ? mx : mn;
    tile[t & 31][s_local] = fmaxf(0.f, sc * v + sh);
  }
  __syncthreads();
#pragma unroll
  for (int p = 0; p < 4; ++p) {
    int c = c0 + (t >> 5) + p * 8;
    int s = s0 + (t & 31);
    out1[(size_t)b * 131072 + (size_t)c * 1024 + s] = tile[(t >> 5) + p * 8][t & 31];
  }
}

extern "C" void kernel_launch(void* const* d_in, const int* in_sizes, int n_in,
                              void* d_out, int out_size, void* d_ws, size_t ws_size,
                              hipStream_t stream) {
  (void)in_sizes; (void)n_in; (void)out_size;
  const float* xyz    = (const float*)d_in[0];
  const float* points = (const float*)d_in[1];
  const float* w0  = (const float*)d_in[2];
  const float* b0  = (const float*)d_in[3];
  const float* g0  = (const float*)d_in[4];
  const float* be0 = (const float*)d_in[5];
  const float* w1  = (const float*)d_in[6];
  const float* b1  = (const float*)d_in[7];
  const float* g1  = (const float*)d_in[8];
  const float* be1 = (const float*)d_in[9];
  const float* w2  = (const float*)d_in[10];
  const float* b2  = (const float*)d_in[11];
  const float* g2  = (const float*)d_in[12];
  const float* be2 = (const float*)d_in[13];
  float* out  = (float*)d_out;
  float* out0 = out;
  float* out1 = out + 49152;
  float* out2 = out + 49152 + 2097152;
  char* ws = (char*)d_ws;
  const size_t OFF_PT    = 0;         // 8388608
  const size_t OFF_XYZ4  = 8388608;   // 1048576
  const size_t OFF_FPS   = 9699328;   // 65536
  const size_t OFF_BALL  = 9764864;   // 2097152
  const size_t OFF_XBUF  = 11862016;  // 67108864 (tail-aliased as max/min store by k_gemm3)
  const size_t OFF_PART  = 78970880;  // 8388608
  const size_t OFF_SC    = 87359488;  // 4096
  const size_t OFF_WB    = 87363584;  // 36864
  const size_t OFF_FLAGS = 87400448;  // 8192
  const size_t NEED      = 87408640;
  if (ws_size < NEED) return;
  unsigned short* pT   = (unsigned short*)(ws + OFF_PT);
  float4* xyz4 = (float4*)(ws + OFF_XYZ4);
  int* fpsidx  = (int*)(ws + OFF_FPS);
  int* ballidx = (int*)(ws + OFF_BALL);
  unsigned short* xbuf = (unsigned short*)(ws + OFF_XBUF);
  float* part  = (float*)(ws + OFF_PART);
  float* scb   = (float*)(ws + OFF_SC);
  float *sc1 = scb, *sh1 = scb + 128, *sc2 = scb + 256, *sh2 = scb + 384,
        *sc3 = scb + 512, *sh3 = scb + 640;
  unsigned short* wb0 = (unsigned short*)(ws + OFF_WB);
  unsigned short* wb1 = wb0 + 6144;
  unsigned short* wb2 = wb1 + 4096;
  int* flags = (int*)(ws + OFF_FLAGS);
  int* prog = flags;            // [16]
  int* ballprog = flags + 64;   // [1024]

  hipMemsetAsync(ws + OFF_FLAGS, 0, 8192, stream);

  int nb = 0;
  hipOccupancyMaxActiveBlocksPerMultiprocessor(&nb, reinterpret_cast<const void*>(k_mega), 256, 0);
  int G = (nb >= 1) ? 256 : 32;   // 256 blocks on 256 CUs: FPS gets dedicated CUs

  MegaP P;
  P.xyz = xyz; P.points = points;
  P.out0 = out0; P.out2 = out2;
  P.fpsidx = fpsidx;
  P.pT = pT; P.xyz4 = xyz4;
  P.w0 = w0; P.w1 = w1; P.w2 = w2;
  P.wb0 = wb0; P.wb1 = wb1; P.wb2 = wb2;
  P.b0 = b0;
  P.xbuf = xbuf; P.part = part;
  P.bidx = ballidx;
  P.prog = prog; P.ballprog = ballprog;
  P.nc = G - 16;
  void* args[] = { &P };
  hipLaunchCooperativeKernel(reinterpret_cast<void*>(k_mega), dim3(G), dim3(256), args, 0, stream);

  k_red<<<64, 256, 0, stream>>>(part, 8192, 64, g0, be0, sc1, sh1);
  k_gemm2<<<8192, 256, 0, stream>>>(xbuf, wb1, b1, sc1, sh1, part);
  k_red<<<64, 256, 0, stream>>>(part, 8192, 64, g1, be1, sc2, sh2);
  k_gemm3<<<8192, 256, 0, stream>>>(xbuf, wb2, b2, sc2, sh2, part);
  k_red<<<128, 256, 0, stream>>>(part, 8192, 128, g2, be2, sc3, sh3);
  k_fin<<<2048, 256, 0, stream>>>((const float*)xbuf, sc3, sh3, out1);
}

// Round 11
// 814.723 us; speedup vs baseline: 1.4833x; 1.3926x over previous
//
#include <hip/hip_runtime.h>

using f32x4  = __attribute__((ext_vector_type(4))) float;
using short8 = __attribute__((ext_vector_type(8))) short;
using u64x2  = __attribute__((ext_vector_type(2))) unsigned long long;

__device__ __forceinline__ unsigned short f2bf(float f) {
  unsigned u = __builtin_bit_cast(unsigned, f);
  u = (u + 0x7FFFu + ((u >> 16) & 1u)) >> 16;
  return (unsigned short)u;
}
__device__ __forceinline__ float bf2f(unsigned short s) {
  return __builtin_bit_cast(float, ((unsigned)s) << 16);
}
__device__ __forceinline__ double u2d(unsigned long long u) {
  return __builtin_bit_cast(double, u);
}
__device__ __forceinline__ unsigned long long d2u(double d) {
  return __builtin_bit_cast(unsigned long long, d);
}
__device__ __forceinline__ unsigned cvt_pk_bf16(float lo, float hi) {
  unsigned r;
  asm("v_cvt_pk_bf16_f32 %0, %1, %2" : "=v"(r) : "v"(lo), "v"(hi));
  return r;
}

// DPP f64 max (reduction; non-receiving lanes get 0 which is < any candidate).
template <int CTRL>
__device__ __forceinline__ double dpp_max_f64(double best) {
  unsigned long long u = d2u(best);
  int lo32 = (int)(unsigned)u;
  int hi32 = (int)(unsigned)(u >> 32);
  int plo = __builtin_amdgcn_update_dpp(0, lo32, CTRL, 0xF, 0xF, true);
  int phi = __builtin_amdgcn_update_dpp(0, hi32, CTRL, 0xF, 0xF, true);
  unsigned long long p =
      ((unsigned long long)(unsigned)phi << 32) | (unsigned long long)(unsigned)plo;
  return fmax(best, u2d(p));
}
// DPP f64 min (bound_ctrl=false: non-receiving lanes keep self).
template <int CTRL>
__device__ __forceinline__ double dpp_min_f64(double v) {
  unsigned long long u = d2u(v);
  int lo32 = (int)(unsigned)u;
  int hi32 = (int)(unsigned)(u >> 32);
  int plo = __builtin_amdgcn_update_dpp(lo32, lo32, CTRL, 0xF, 0xF, false);
  int phi = __builtin_amdgcn_update_dpp(hi32, hi32, CTRL, 0xF, 0xF, false);
  unsigned long long p =
      ((unsigned long long)(unsigned)phi << 32) | (unsigned long long)(unsigned)plo;
  return fmin(v, u2d(p));
}

// ---------------- Merged FPS + prep: blocks 0-15 = FPS (1/batch); 16-1039 = points transpose;
// 1040 = weight bf16 conversion. FPS occupies <=16 CUs for its duration; prep hides under it.
union SmemFP {
  struct {
    float4 sp4[4096];
    unsigned long long scand[2][16];
    int sfar[1024];
  } f;
  float tile[64][65];
};

__global__ __launch_bounds__(256, 1) void k_fp(const float* __restrict__ xyz,
                                               const float* __restrict__ points,
                                               float* __restrict__ out0,
                                               float* __restrict__ out2,
                                               int* __restrict__ fpsidx,
                                               float4* __restrict__ nq4,
                                               unsigned short* __restrict__ pT,
                                               float4* __restrict__ xyz4,
                                               const float* __restrict__ w0,
                                               const float* __restrict__ w1,
                                               const float* __restrict__ w2,
                                               unsigned short* __restrict__ wb0,
                                               unsigned short* __restrict__ wb1,
                                               unsigned short* __restrict__ wb2) {
  __shared__ SmemFP sm;
  int t = threadIdx.x, blk = blockIdx.x;
  if (blk >= 16) {
    int pb = blk - 16;
    if (pb == 1024) {   // weights
      for (int e = t; e < 64 * 96; e += 256) {
        int o = e / 96, k = e - o * 96;
        float v = (k < 64) ? w0[o * 67 + 3 + k] : ((k < 67) ? w0[o * 67 + (k - 64)] : 0.f);
        wb0[e] = f2bf(v);
      }
      for (int e = t; e < 4096; e += 256) wb1[e] = f2bf(w1[e]);
      for (int e = t; e < 8192; e += 256) wb2[e] = f2bf(w2[e]);
      return;
    }
    int b = pb >> 6, n0 = (pb & 63) << 6;
#pragma unroll
    for (int p = 0; p < 16; ++p) {
      int c = p * 4 + (t >> 6);
      sm.tile[c][t & 63] = points[(size_t)b * 262144 + (size_t)c * 4096 + n0 + (t & 63)];
    }
    if (t < 64) {
      int n = n0 + t;
      float x = xyz[(size_t)b * 12288 + n];
      float y = xyz[(size_t)b * 12288 + 4096 + n];
      float z = xyz[(size_t)b * 12288 + 8192 + n];
      float ps = __fadd_rn(__fadd_rn(__fmul_rn(x, x), __fmul_rn(y, y)), __fmul_rn(z, z));
      xyz4[(size_t)b * 4096 + n] = make_float4(x, y, z, ps);
    }
    __syncthreads();
    int nl = t >> 2, coff = (t & 3) * 16;
    unsigned v[8];
#pragma unroll
    for (int j = 0; j < 8; ++j)
      v[j] = cvt_pk_bf16(sm.tile[coff + 2 * j][nl], sm.tile[coff + 2 * j + 1][nl]);
    uint4* dst = reinterpret_cast<uint4*>(pT + ((size_t)b * 4096 + n0 + nl) * 64 + coff);
    dst[0] = make_uint4(v[0], v[1], v[2], v[3]);
    dst[1] = make_uint4(v[4], v[5], v[6], v[7]);
    return;
  }
  // ---- FPS path: validated distance chain; NEW exact-max tail (read-1 + DPP stage-2) ----
  int b = blk;
  float px[16], py[16], pz[16], dist[16];
#pragma unroll
  for (int j = 0; j < 16; ++j) {
    int n = t + (j << 8);
    float x = xyz[(size_t)b * 12288 + n];
    float y = xyz[(size_t)b * 12288 + 4096 + n];
    float z = xyz[(size_t)b * 12288 + 8192 + n];
    px[j] = x; py[j] = y; pz[j] = z; dist[j] = 1e10f;
    sm.f.sp4[n] = make_float4(x, y, z, 0.f);
  }
  __syncthreads();
#pragma unroll
  for (int j = 0; j < 16; ++j) {
    asm volatile("" : "+v"(px[j]), "+v"(py[j]), "+v"(pz[j]));
  }
  unsigned nt = ~(unsigned)t;
  int far = 0;
  float cx = sm.f.sp4[0].x, cy = sm.f.sp4[0].y, cz = sm.f.sp4[0].z;
  for (int it = 0; it < 1024; ++it) {
    if (t == 0) sm.f.sfar[it] = far;
    double best0 = 0.0, best1 = 0.0;
#pragma unroll
    for (int j = 0; j < 16; ++j) {
      float dx = __fsub_rn(px[j], cx);
      float dy = __fsub_rn(py[j], cy);
      float dz = __fsub_rn(pz[j], cz);
      float d  = __fadd_rn(__fadd_rn(__fmul_rn(dx, dx), __fmul_rn(dy, dy)), __fmul_rn(dz, dz));
      float nd = fminf(dist[j], d);
      dist[j] = nd;
      unsigned long long cand =
          ((unsigned long long)__builtin_bit_cast(unsigned, nd) << 32) |
          (unsigned long long)(nt - (unsigned)(j << 8));   // ~(t + j*256)
      if (j & 1) best1 = fmax(best1, u2d(cand));
      else       best0 = fmax(best0, u2d(cand));
    }
    double best = fmax(best0, best1);
    best = dpp_max_f64<0xB1>(best);   // quad xor1
    best = dpp_max_f64<0x4E>(best);   // quad xor2
    best = dpp_max_f64<0x124>(best);  // row_ror:4
    best = dpp_max_f64<0x128>(best);  // row_ror:8 -> all 16 lanes hold row max
    int pb = it & 1;
    if ((t & 15) == 0) sm.f.scand[pb][t >> 4] = d2u(best);
    __syncthreads();
    // stage 2: each lane reads ONE candidate (16 u64 = 32 banks, cross-row broadcast),
    // then the same validated 4-level DPP max -> every lane holds the global max.
    double g = u2d(sm.f.scand[pb][t & 15]);
    g = dpp_max_f64<0xB1>(g);
    g = dpp_max_f64<0x4E>(g);
    g = dpp_max_f64<0x124>(g);
    g = dpp_max_f64<0x128>(g);
    unsigned long long bw = d2u(g);
    int n = (int)(~(unsigned)bw) & 4095;
    far = n;
    float4 c4 = sm.f.sp4[n];
    cx = c4.x; cy = c4.y; cz = c4.z;
  }
  __syncthreads();
#pragma unroll
  for (int h = 0; h < 4; ++h) {
    int k = (h << 8) + t;
    int fr = sm.f.sfar[k];
    float4 p = sm.f.sp4[fr];
    float x = p.x, y = p.y, z = p.z;
    fpsidx[(b << 10) + k] = fr;
    out2[(b << 10) + k] = (float)fr;
    out0[(size_t)b * 3072 + k]        = x;
    out0[(size_t)b * 3072 + 1024 + k] = y;
    out0[(size_t)b * 3072 + 2048 + k] = z;
    float ps = __fadd_rn(__fadd_rn(__fmul_rn(x, x), __fmul_rn(y, y)), __fmul_rn(z, z));
    nq4[(b << 10) + k] = make_float4(x, y, z, ps);
  }
}

// ---------------- Ball query (validated r8): packed-u64 candidates; sorted-head pop extraction.
#define BCAP 384
__global__ __launch_bounds__(256) void k_ball(const float4* __restrict__ xyz4,
                                              const int* __restrict__ fpsidx,
                                              int* __restrict__ ballidx) {
  __shared__ __align__(16) float4 sp[4096];
  __shared__ unsigned long long spk[4][BCAP];
  const unsigned long long INVP = 0x7149F2CAFFFFFFFFull;  // (bits(1e30f)<<32)|~0 : > any valid
  int t = threadIdx.x, blk = blockIdx.x;
  int b = blk >> 6;
  for (int i = t; i < 4096; i += 256) sp[i] = xyz4[(size_t)b * 4096 + i];
  __syncthreads();
  int lane = t & 63, wid = t >> 6;
  for (int r = 0; r < 4; ++r) {
    int q = blk * 16 + r * 4 + wid;
    int qi = fpsidx[q];
    float4 Q = sp[qi];
    float qx = Q.x, qy = Q.y, qz = Q.z, qs = Q.w;
    int cnt = 0;
    for (int i = 0; i < 64; ++i) {
      int n = (i << 6) + lane;
      float4 P = sp[n];
      float dot = __fadd_rn(__fadd_rn(__fmul_rn(qx, P.x), __fmul_rn(qy, P.y)), __fmul_rn(qz, P.z));
      float d   = __fadd_rn(__fadd_rn(__fmul_rn(-2.f, dot), qs), P.w);   // exact np expansion
      bool in = (d <= 0.04f);   // matches  !(d > f32(0.04))
      unsigned long long m = __ballot(in);
      int pos = cnt + (int)__popcll(m & ((1ull << lane) - 1ull));
      if (in && pos < BCAP)
        spk[wid][pos] = ((unsigned long long)__builtin_bit_cast(unsigned, d) << 32) | (unsigned)n;
      cnt += (int)__popcll(m);
    }
    if (cnt > BCAP) cnt = BCAP;
    double c0, c1, c2, c3, c4, c5;
    {
      int s0 = lane, s1 = lane + 64, s2 = lane + 128, s3 = lane + 192, s4 = lane + 256, s5 = lane + 320;
      c0 = (s0 < cnt) ? u2d(spk[wid][s0]) : u2d(INVP);
      c1 = (s1 < cnt) ? u2d(spk[wid][s1]) : u2d(INVP);
      c2 = (s2 < cnt) ? u2d(spk[wid][s2]) : u2d(INVP);
      c3 = (s3 < cnt) ? u2d(spk[wid][s3]) : u2d(INVP);
      c4 = (s4 < cnt) ? u2d(spk[wid][s4]) : u2d(INVP);
      c5 = (s5 < cnt) ? u2d(spk[wid][s5]) : u2d(INVP);
    }
    // 15-CE insertion-sort network (ascending); all values finite positive doubles.
#define CE(a, b) { double mn_ = fmin(a, b), mx_ = fmax(a, b); a = mn_; b = mx_; }
    CE(c0, c1);
    CE(c1, c2); CE(c0, c1);
    CE(c2, c3); CE(c1, c2); CE(c0, c1);
    CE(c3, c4); CE(c2, c3); CE(c1, c2); CE(c0, c1);
    CE(c4, c5); CE(c3, c4); CE(c2, c3); CE(c1, c2); CE(c0, c1);
#undef CE
    int firstI = 0;
#pragma unroll 1
    for (int rr = 0; rr < 32; ++rr) {
      double h = c0;
      h = dpp_min_f64<0xB1>(h);    // quad xor1
      h = dpp_min_f64<0x4E>(h);    // quad xor2
      h = dpp_min_f64<0x124>(h);   // row_ror:4
      h = dpp_min_f64<0x128>(h);   // row_ror:8 -> row min in all 16 lanes
      unsigned long long hu = d2u(h);
      int lo = (int)(unsigned)hu, hi = (int)(unsigned)(hu >> 32);
      unsigned long long r0 = ((unsigned long long)(unsigned)__builtin_amdgcn_readlane(hi, 0)  << 32) | (unsigned)__builtin_amdgcn_readlane(lo, 0);
      unsigned long long r1 = ((unsigned long long)(unsigned)__builtin_amdgcn_readlane(hi, 16) << 32) | (unsigned)__builtin_amdgcn_readlane(lo, 16);
      unsigned long long r2 = ((unsigned long long)(unsigned)__builtin_amdgcn_readlane(hi, 32) << 32) | (unsigned)__builtin_amdgcn_readlane(lo, 32);
      unsigned long long r3 = ((unsigned long long)(unsigned)__builtin_amdgcn_readlane(hi, 48) << 32) | (unsigned)__builtin_amdgcn_readlane(lo, 48);
      double w = fmin(fmin(u2d(r0), u2d(r1)), fmin(u2d(r2), u2d(r3)));
      unsigned long long wu = d2u(w);
      int wi = (int)(unsigned)wu;
      if (rr == 0) firstI = wi;
      int outv = (wu < INVP) ? wi : firstI;   // pad with first when exhausted
      if (lane == 0) ballidx[(size_t)q * 32 + rr] = outv;
      if (d2u(c0) == wu) {   // unique winner pops its head (idx uniqueness => no collision)
        c0 = c1; c1 = c2; c2 = c3; c3 = c4; c4 = c5; c5 = u2d(INVP);
      }
    }
  }
}

// ---------------- Layer1 (validated r8): gather + bf16 MFMA GEMM (K=96), x1 bf16 + stats partials
__global__ __launch_bounds__(256) void k_gemm1(const unsigned short* __restrict__ pT,
    const float4* __restrict__ xyz4, const float4* __restrict__ nq4,
    const int* __restrict__ bidx, const unsigned short* __restrict__ wb,
    const float* __restrict__ bia, unsigned short* __restrict__ xbuf,
    float* __restrict__ part) {
  __shared__ unsigned short A[64][104];
  __shared__ unsigned short W[64][104];
  __shared__ float sred[4][2][64];
  int t = threadIdx.x, blk = blockIdx.x;
  int b = blk >> 9;
  for (int e = t; e < 768; e += 256) {
    int o = e / 12, k8 = e - o * 12;
    *reinterpret_cast<uint4*>(&W[o][k8 * 8]) = reinterpret_cast<const uint4*>(wb)[e];
  }
  {
    int rt = t >> 2, sub = t & 3;
    int q = (blk << 1) + (rt >> 5);
    int n = bidx[(size_t)q * 32 + (rt & 31)];
    const uint4* src = reinterpret_cast<const uint4*>(pT + ((size_t)(b * 4096 + n)) * 64 + sub * 16);
    uint4 v0 = src[0], v1 = src[1];
    *reinterpret_cast<uint4*>(&A[rt][sub * 16])     = v0;
    *reinterpret_cast<uint4*>(&A[rt][sub * 16 + 8]) = v1;
    if (sub == 0) {
      float4 P = xyz4[(size_t)b * 4096 + n];
      float4 Qc = nq4[q];
      A[rt][64] = f2bf(__fsub_rn(P.x, Qc.x));
      A[rt][65] = f2bf(__fsub_rn(P.y, Qc.y));
      A[rt][66] = f2bf(__fsub_rn(P.z, Qc.z));
    } else if (sub == 1) {
#pragma unroll
      for (int k = 67; k < 96; ++k) A[rt][k] = 0;
    }
  }
  __syncthreads();
  int lane = t & 63, wid = t >> 6;
  int cl = lane & 15, rg = lane >> 4;
  int rowb = (wid << 4) + cl, ko = rg << 3;
  f32x4 acc[4] = {};
#pragma unroll
  for (int ks = 0; ks < 96; ks += 32) {
    short8 a = *reinterpret_cast<const short8*>(&A[rowb][ks + ko]);
#pragma unroll
    for (int nt = 0; nt < 4; ++nt) {
      short8 bb = *reinterpret_cast<const short8*>(&W[nt * 16 + cl][ks + ko]);
      acc[nt] = __builtin_amdgcn_mfma_f32_16x16x32_bf16(a, bb, acc[nt], 0, 0, 0);
    }
  }
#pragma unroll
  for (int nt = 0; nt < 4; ++nt) {
    int ch = nt * 16 + cl;
    float bv = bia[ch];
    float v0 = acc[nt][0] + bv, v1 = acc[nt][1] + bv, v2 = acc[nt][2] + bv, v3 = acc[nt][3] + bv;
    size_t gr = (size_t)blk * 64 + (wid << 4) + (rg << 2);
    xbuf[(gr + 0) * 64 + ch] = f2bf(v0);
    xbuf[(gr + 1) * 64 + ch] = f2bf(v1);
    xbuf[(gr + 2) * 64 + ch] = f2bf(v2);
    xbuf[(gr + 3) * 64 + ch] = f2bf(v3);
    float s1 = (v0 + v1) + (v2 + v3);
    float s2 = (v0 * v0 + v1 * v1) + (v2 * v2 + v3 * v3);
    s1 += __shfl_xor(s1, 16); s1 += __shfl_xor(s1, 32);
    s2 += __shfl_xor(s2, 16); s2 += __shfl_xor(s2, 32);
    if (rg == 0) { sred[wid][0][ch] = s1; sred[wid][1][ch] = s2; }
  }
  __syncthreads();
  if (t < 128) {
    int ch = t & 63, wh = t >> 6;
    float v = sred[0][wh][ch] + sred[1][wh][ch] + sred[2][wh][ch] + sred[3][wh][ch];
    part[(size_t)blk * 128 + ch * 2 + wh] = v;
  }
}

// ---------------- stats partial reduce -> folded BN scale/shift (validated) ----------------
__global__ __launch_bounds__(256) void k_red(const float* __restrict__ part, int nblk, int nch,
    const float* __restrict__ gamma, const float* __restrict__ beta,
    float* __restrict__ scale, float* __restrict__ shift) {
  int c = blockIdx.x, t = threadIdx.x;
  int stride = 2 * nch;
  float s1 = 0.f, s2 = 0.f;
  for (int i = t; i < nblk; i += 256) {
    s1 += part[(size_t)i * stride + 2 * c];
    s2 += part[(size_t)i * stride + 2 * c + 1];
  }
  __shared__ float r1[256], r2[256];
  r1[t] = s1; r2[t] = s2;
  __syncthreads();
  for (int o = 128; o > 0; o >>= 1) {
    if (t < o) { r1[t] += r1[t + o]; r2[t] += r2[t + o]; }
    __syncthreads();
  }
  if (t == 0) {
    const float N = 524288.f;
    float mu = r1[0] / N;
    float var = r2[0] / N - mu * mu;
    float a = gamma[c] / sqrtf(var + 1e-5f);
    scale[c] = a;
    shift[c] = beta[c] - a * mu;
  }
}

// ---------------- Layer2 (validated) ----------------
__global__ __launch_bounds__(256) void k_gemm2(unsigned short* __restrict__ xbuf,
    const unsigned short* __restrict__ wb, const float* __restrict__ bia,
    const float* __restrict__ sc, const float* __restrict__ sh,
    float* __restrict__ part) {
  __shared__ unsigned short A[64][72];
  __shared__ unsigned short W[64][72];
  __shared__ float ssc[64], ssh[64];
  __shared__ float sred[4][2][64];
  int t = threadIdx.x, blk = blockIdx.x;
  if (t < 64) { ssc[t] = sc[t]; ssh[t] = sh[t]; }
  __syncthreads();
  for (int e = t; e < 512; e += 256) {
    int o = e >> 3, k8 = e & 7;
    *reinterpret_cast<uint4*>(&W[o][k8 * 8]) = reinterpret_cast<const uint4*>(wb)[e];
  }
  {
    int rt = t >> 2, sub = t & 3;
    size_t gr = (size_t)blk * 64 + rt;
    const uint4* src = reinterpret_cast<const uint4*>(xbuf + gr * 64 + sub * 16);
    uint4 v0 = src[0], v1 = src[1];
    unsigned wv[8] = {v0.x, v0.y, v0.z, v0.w, v1.x, v1.y, v1.z, v1.w};
    unsigned pk[8];
#pragma unroll
    for (int j = 0; j < 8; ++j) {
      int c = sub * 16 + 2 * j;
      float x0 = bf2f((unsigned short)(wv[j] & 0xffffu));
      float x1 = bf2f((unsigned short)(wv[j] >> 16));
      float a0 = fmaxf(0.f, ssc[c] * x0 + ssh[c]);
      float a1 = fmaxf(0.f, ssc[c + 1] * x1 + ssh[c + 1]);
      pk[j] = cvt_pk_bf16(a0, a1);
    }
    *reinterpret_cast<uint4*>(&A[rt][sub * 16])     = make_uint4(pk[0], pk[1], pk[2], pk[3]);
    *reinterpret_cast<uint4*>(&A[rt][sub * 16 + 8]) = make_uint4(pk[4], pk[5], pk[6], pk[7]);
  }
  __syncthreads();
  int lane = t & 63, wid = t >> 6;
  int cl = lane & 15, rg = lane >> 4;
  int rowb = (wid << 4) + cl, ko = rg << 3;
  f32x4 acc[4] = {};
#pragma unroll
  for (int ks = 0; ks < 64; ks += 32) {
    short8 a = *reinterpret_cast<const short8*>(&A[rowb][ks + ko]);
#pragma unroll
    for (int nt = 0; nt < 4; ++nt) {
      short8 bb = *reinterpret_cast<const short8*>(&W[nt * 16 + cl][ks + ko]);
      acc[nt] = __builtin_amdgcn_mfma_f32_16x16x32_bf16(a, bb, acc[nt], 0, 0, 0);
    }
  }
#pragma unroll
  for (int nt = 0; nt < 4; ++nt) {
    int ch = nt * 16 + cl;
    float bv = bia[ch];
    float v0 = acc[nt][0] + bv, v1 = acc[nt][1] + bv, v2 = acc[nt][2] + bv, v3 = acc[nt][3] + bv;
    size_t gr = (size_t)blk * 64 + (wid << 4) + (rg << 2);
    xbuf[(gr + 0) * 64 + ch] = f2bf(v0);
    xbuf[(gr + 1) * 64 + ch] = f2bf(v1);
    xbuf[(gr + 2) * 64 + ch] = f2bf(v2);
    xbuf[(gr + 3) * 64 + ch] = f2bf(v3);
    float s1 = (v0 + v1) + (v2 + v3);
    float s2 = (v0 * v0 + v1 * v1) + (v2 * v2 + v3 * v3);
    s1 += __shfl_xor(s1, 16); s1 += __shfl_xor(s1, 32);
    s2 += __shfl_xor(s2, 16); s2 += __shfl_xor(s2, 32);
    if (rg == 0) { sred[wid][0][ch] = s1; sred[wid][1][ch] = s2; }
  }
  __syncthreads();
  if (t < 128) {
    int ch = t & 63, wh = t >> 6;
    float v = sred[0][wh][ch] + sred[1][wh][ch] + sred[2][wh][ch] + sred[3][wh][ch];
    part[(size_t)blk * 128 + ch * 2 + wh] = v;
  }
}

// ---------------- Layer3 single pass (validated): GEMM + stats + per-(q,ch) max/min ----------------
__global__ __launch_bounds__(256) void k_gemm3(unsigned short* xbuf,
    const unsigned short* __restrict__ wb, const float* __restrict__ bia,
    const float* __restrict__ sc2, const float* __restrict__ sh2,
    float* __restrict__ part) {
  __shared__ unsigned short A[64][72];
  __shared__ unsigned short W[128][72];
  __shared__ float ssc[64], ssh[64];
  __shared__ float sred[4][4][128];
  int t = threadIdx.x, blk = blockIdx.x;
  if (t < 64) { ssc[t] = sc2[t]; ssh[t] = sh2[t]; }
  __syncthreads();
  for (int e = t; e < 1024; e += 256) {
    int o = e >> 3, k8 = e & 7;
    *reinterpret_cast<uint4*>(&W[o][k8 * 8]) = reinterpret_cast<const uint4*>(wb)[e];
  }
  {
    int rt = t >> 2, sub = t & 3;
    size_t gr = (size_t)blk * 64 + rt;
    const uint4* src = reinterpret_cast<const uint4*>(xbuf + gr * 64 + sub * 16);
    uint4 v0 = src[0], v1 = src[1];
    unsigned wv[8] = {v0.x, v0.y, v0.z, v0.w, v1.x, v1.y, v1.z, v1.w};
    unsigned pk[8];
#pragma unroll
    for (int j = 0; j < 8; ++j) {
      int c = sub * 16 + 2 * j;
      float x0 = bf2f((unsigned short)(wv[j] & 0xffffu));
      float x1 = bf2f((unsigned short)(wv[j] >> 16));
      float a0 = fmaxf(0.f, ssc[c] * x0 + ssh[c]);
      float a1 = fmaxf(0.f, ssc[c + 1] * x1 + ssh[c + 1]);
      pk[j] = cvt_pk_bf16(a0, a1);
    }
    *reinterpret_cast<uint4*>(&A[rt][sub * 16])     = make_uint4(pk[0], pk[1], pk[2], pk[3]);
    *reinterpret_cast<uint4*>(&A[rt][sub * 16 + 8]) = make_uint4(pk[4], pk[5], pk[6], pk[7]);
  }
  __syncthreads();
  int lane = t & 63, wid = t >> 6;
  int cl = lane & 15, rg = lane >> 4;
  int rowb = (wid << 4) + cl, ko = rg << 3;
  f32x4 acc[8] = {};
#pragma unroll
  for (int ks = 0; ks < 64; ks += 32) {
    short8 a = *reinterpret_cast<const short8*>(&A[rowb][ks + ko]);
#pragma unroll
    for (int nt = 0; nt < 8; ++nt) {
      short8 bb = *reinterpret_cast<const short8*>(&W[nt * 16 + cl][ks + ko]);
      acc[nt] = __builtin_amdgcn_mfma_f32_16x16x32_bf16(a, bb, acc[nt], 0, 0, 0);
    }
  }
#pragma unroll
  for (int nt = 0; nt < 8; ++nt) {
    int ch = nt * 16 + cl;
    float bv = bia[ch];
    float v0 = acc[nt][0] + bv, v1 = acc[nt][1] + bv, v2 = acc[nt][2] + bv, v3 = acc[nt][3] + bv;
    float s1 = (v0 + v1) + (v2 + v3);
    float s2 = (v0 * v0 + v1 * v1) + (v2 * v2 + v3 * v3);
    float mx = fmaxf(fmaxf(v0, v1), fmaxf(v2, v3));
    float mn = fminf(fminf(v0, v1), fminf(v2, v3));
    s1 += __shfl_xor(s1, 16); s1 += __shfl_xor(s1, 32);
    s2 += __shfl_xor(s2, 16); s2 += __shfl_xor(s2, 32);
    mx = fmaxf(mx, __shfl_xor(mx, 16)); mx = fmaxf(mx, __shfl_xor(mx, 32));
    mn = fminf(mn, __shfl_xor(mn, 16)); mn = fminf(mn, __shfl_xor(mn, 32));
    if (rg == 0) {
      sred[wid][0][ch] = s1; sred[wid][1][ch] = s2;
      sred[wid][2][ch] = mx; sred[wid][3][ch] = mn;
    }
  }
  __syncthreads();
  {
    int ch = t & 127, wh = t >> 7;   // wh doubles as qq for max/min
    part[(size_t)blk * 256 + ch * 2 + wh] =
        sred[0][wh][ch] + sred[1][wh][ch] + sred[2][wh][ch] + sred[3][wh][ch];
    float mx = fmaxf(sred[2 * wh][2][ch], sred[2 * wh + 1][2][ch]);
    float mn = fminf(sred[2 * wh][3][ch], sred[2 * wh + 1][3][ch]);
    float* mm = reinterpret_cast<float*>(xbuf) + (size_t)blk * 2048;
    mm[wh * 256 + ch]       = mx;
    mm[wh * 256 + 128 + ch] = mn;
  }
}

// ---------------- final (validated): out1[b,c,s] = relu(sc3*(sc3>=0?max:min)+sh3), fused transpose
__global__ __launch_bounds__(256) void k_fin(const float* __restrict__ mm,
                                             const float* __restrict__ sc3,
                                             const float* __restrict__ sh3,
                                             float* __restrict__ out1) {
  __shared__ float tile[32][33];
  int t = threadIdx.x, blk = blockIdx.x;
  int b = blk >> 7, rem = blk & 127, ct = rem >> 5, st = rem & 31;
  int c0 = ct * 32, s0 = st * 32;
#pragma unroll
  for (int p = 0; p < 4; ++p) {
    int s_local = (t >> 5) + p * 8;
    int c = c0 + (t & 31);
    int q = (b << 10) + s0 + s_local;
    size_t base = (size_t)(q >> 1) * 2048 + (size_t)(q & 1) * 256;
    float mx = mm[base + c];
    float mn = mm[base + 128 + c];
    float sc = sc3[c], sh = sh3[c];
    float v = (sc >= 0.f) ? mx : mn;
    tile[t & 31][s_local] = fmaxf(0.f, sc * v + sh);
  }
  __syncthreads();
#pragma unroll
  for (int p = 0; p < 4; ++p) {
    int c = c0 + (t >> 5) + p * 8;
    int s = s0 + (t & 31);
    out1[(size_t)b * 131072 + (size_t)c * 1024 + s] = tile[(t >> 5) + p * 8][t & 31];
  }
}

extern "C" void kernel_launch(void* const* d_in, const int* in_sizes, int n_in,
                              void* d_out, int out_size, void* d_ws, size_t ws_size,
                              hipStream_t stream) {
  (void)in_sizes; (void)n_in; (void)out_size;
  const float* xyz    = (const float*)d_in[0];
  const float* points = (const float*)d_in[1];
  const float* w0  = (const float*)d_in[2];
  const float* b0  = (const float*)d_in[3];
  const float* g0  = (const float*)d_in[4];
  const float* be0 = (const float*)d_in[5];
  const float* w1  = (const float*)d_in[6];
  const float* b1  = (const float*)d_in[7];
  const float* g1  = (const float*)d_in[8];
  const float* be1 = (const float*)d_in[9];
  const float* w2  = (const float*)d_in[10];
  const float* b2  = (const float*)d_in[11];
  const float* g2  = (const float*)d_in[12];
  const float* be2 = (const float*)d_in[13];
  float* out  = (float*)d_out;
  float* out0 = out;
  float* out1 = out + 49152;
  float* out2 = out + 49152 + 2097152;
  char* ws = (char*)d_ws;
  const size_t OFF_PT    = 0;         // 8388608
  const size_t OFF_XYZ4  = 8388608;   // 1048576
  const size_t OFF_NQ4   = 9437184;   // 262144
  const size_t OFF_FPS   = 9699328;   // 65536
  const size_t OFF_BALL  = 9764864;   // 2097152
  const size_t OFF_XBUF  = 11862016;  // 67108864 (tail-aliased as max/min store by k_gemm3)
  const size_t OFF_PART  = 78970880;  // 8388608
  const size_t OFF_SC    = 87359488;  // 4096
  const size_t OFF_WB    = 87363584;  // 36864
  const size_t NEED      = 87400448;
  if (ws_size < NEED) return;
  unsigned short* pT   = (unsigned short*)(ws + OFF_PT);
  float4* xyz4 = (float4*)(ws + OFF_XYZ4);
  float4* nq4  = (float4*)(ws + OFF_NQ4);
  int* fpsidx  = (int*)(ws + OFF_FPS);
  int* ballidx = (int*)(ws + OFF_BALL);
  unsigned short* xbuf = (unsigned short*)(ws + OFF_XBUF);
  float* part  = (float*)(ws + OFF_PART);
  float* scb   = (float*)(ws + OFF_SC);
  float *sc1 = scb, *sh1 = scb + 128, *sc2 = scb + 256, *sh2 = scb + 384,
        *sc3 = scb + 512, *sh3 = scb + 640;
  unsigned short* wb0 = (unsigned short*)(ws + OFF_WB);
  unsigned short* wb1 = wb0 + 6144;
  unsigned short* wb2 = wb1 + 4096;

  k_fp<<<1041, 256, 0, stream>>>(xyz, points, out0, out2, fpsidx, nq4,
                                 pT, xyz4, w0, w1, w2, wb0, wb1, wb2);
  k_ball<<<1024, 256, 0, stream>>>(xyz4, fpsidx, ballidx);
  k_gemm1<<<8192, 256, 0, stream>>>(pT, xyz4, nq4, ballidx, wb0, b0, xbuf, part);
  k_red<<<64, 256, 0, stream>>>(part, 8192, 64, g0, be0, sc1, sh1);
  k_gemm2<<<8192, 256, 0, stream>>>(xbuf, wb1, b1, sc1, sh1, part);
  k_red<<<64, 256, 0, stream>>>(part, 8192, 64, g1, be1, sc2, sh2);
  k_gemm3<<<8192, 256, 0, stream>>>(xbuf, wb2, b2, sc2, sh2, part);
  k_red<<<128, 256, 0, stream>>>(part, 8192, 128, g2, be2, sc3, sh3);
  k_fin<<<2048, 256, 0, stream>>>((const float*)xbuf, sc3, sh3, out1);
}